// Round 6
// baseline (297.120 us; speedup 1.0000x reference)
//
#include <hip/hip_runtime.h>
#include <math.h>

#define NROWS 32768
#define NE    1024
#define CDIM  256
#define ZB_STRIDE 262144

#define ZQ_OFF   0
#define LOSS_OFF 8388608
#define PERP_OFF 8388609
#define ENC_OFF  8388610
#define IDX_OFF  41943042

#define THETA 1.0e-4f

typedef __attribute__((ext_vector_type(8))) short bf16x8;
typedef __attribute__((ext_vector_type(4))) float f32x4;
typedef __attribute__((ext_vector_type(8))) unsigned short ushort8;

// RNE float -> bf16 bits
__device__ __forceinline__ unsigned short f2bf(float f) {
  union { float f; unsigned u; } v; v.f = f;
  unsigned r = v.u + 0x7FFFu + ((v.u >> 16) & 1u);
  return (unsigned short)(r >> 16);
}
__device__ __forceinline__ float bf2f(unsigned short b) {
  union { float f; unsigned u; } v; v.u = ((unsigned)b) << 16;
  return v.f;
}

// async global->LDS, 16B per lane
__device__ __forceinline__ void gl_lds16(const unsigned short* g, char* l) {
  __builtin_amdgcn_global_load_lds(
      (const __attribute__((address_space(1))) unsigned short*)g,
      (__attribute__((address_space(3))) char*)l, 16, 0, 0);
}

// ---------------------------------------------------------------------------
// numpy-pairwise-exact sum of squares (stride 1)
__device__ __forceinline__ float np_sumsq_256_s1(const float* __restrict__ base) {
  float tot[2];
#pragma unroll
  for (int hh = 0; hh < 2; ++hh) {
    float r[8];
#pragma unroll
    for (int j = 0; j < 8; ++j) {
      float x = base[hh * 128 + j];
      r[j] = __fmul_rn(x, x);
    }
    for (int i = 8; i < 128; i += 8) {
#pragma unroll
      for (int j = 0; j < 8; ++j) {
        float x = base[hh * 128 + i + j];
        r[j] = __fadd_rn(r[j], __fmul_rn(x, x));
      }
    }
    tot[hh] = __fadd_rn(__fadd_rn(__fadd_rn(r[0], r[1]), __fadd_rn(r[2], r[3])),
                        __fadd_rn(__fadd_rn(r[4], r[5]), __fadd_rn(r[6], r[7])));
  }
  return __fadd_rn(tot[0], tot[1]);
}

__global__ __launch_bounds__(256) void enorm_kernel(const float* __restrict__ emb,
                                                    float* __restrict__ enorm) {
  int n = blockIdx.x * 256 + threadIdx.x;
  enorm[n] = np_sumsq_256_s1(emb + (size_t)n * CDIM);
}

// emb fp32 -> bf16 hi + lo
__global__ __launch_bounds__(256) void convert_e_kernel(const float* __restrict__ emb,
                                                        unsigned short* __restrict__ ehi,
                                                        unsigned short* __restrict__ elo) {
  int i = (blockIdx.x * 256 + threadIdx.x) * 8;
  ushort8 oh, ol;
#pragma unroll
  for (int j = 0; j < 8; ++j) {
    float x = emb[i + j];
    unsigned short h = f2bf(x);
    oh[j] = h;
    ol[j] = f2bf(__fsub_rn(x, bf2f(h)));
  }
  *reinterpret_cast<ushort8*>(ehi + i) = oh;
  *reinterpret_cast<ushort8*>(elo + i) = ol;
}

// emb[e][c] -> embT[c][e] fp32 (for coalesced repair)
__global__ __launch_bounds__(256) void transpose_e_kernel(const float* __restrict__ emb,
                                                          float* __restrict__ embT) {
  __shared__ float tile[32][33];
  int be = blockIdx.x & 31, bc = blockIdx.x >> 5;
  int tx = threadIdx.x & 31, ty = threadIdx.x >> 5;
#pragma unroll
  for (int i = 0; i < 4; ++i)
    tile[ty + 8 * i][tx] = emb[(size_t)(be * 32 + ty + 8 * i) * 256 + bc * 32 + tx];
  __syncthreads();
#pragma unroll
  for (int i = 0; i < 4; ++i)
    embT[(size_t)(bc * 32 + ty + 8 * i) * 1024 + be * 32 + tx] = tile[tx][ty + 8 * i];
}

// ---------------------------------------------------------------------------
// z (b,c,h,w) fp32 -> zhi,zlo (n,c) bf16 transpose + numpy-exact znorm.
__global__ __launch_bounds__(256) void convert_z_kernel(const float* __restrict__ z,
                                                        unsigned short* __restrict__ zhi,
                                                        unsigned short* __restrict__ zlo,
                                                        float* __restrict__ znorm) {
  __shared__ unsigned short T16[64][266];
  __shared__ unsigned short Tlo[64][266];
  __shared__ float accsF[2][8][16][4];
  const int t = threadIdx.x;
  const int b = blockIdx.x >> 4, hwt = blockIdx.x & 15;
  const int hw0 = hwt * 64;
  const int hw4 = t & 15;          // float4 unit within 64 hw
  const int jj = (t >> 4) & 7;     // np accumulator index
  const int hh = t >> 7;           // half
  const float* zb = z + (size_t)b * ZB_STRIDE + hw0 + hw4 * 4;

  float rr[4];
#pragma unroll
  for (int i = 0; i < 16; ++i) {
    int c = hh * 128 + jj + 8 * i;
    float4 v = *reinterpret_cast<const float4*>(zb + (size_t)c * 1024);
    const float xv[4] = {v.x, v.y, v.z, v.w};
#pragma unroll
    for (int q = 0; q < 4; ++q) {
      float p = __fmul_rn(xv[q], xv[q]);
      rr[q] = (i == 0) ? p : __fadd_rn(rr[q], p);
      unsigned short hbits = f2bf(xv[q]);
      T16[hw4 * 4 + q][c] = hbits;
      Tlo[hw4 * 4 + q][c] = f2bf(__fsub_rn(xv[q], bf2f(hbits)));
    }
  }
#pragma unroll
  for (int q = 0; q < 4; ++q) accsF[hh][jj][hw4][q] = rr[q];
  __syncthreads();

  if (t < 64) {
    const int h4 = t >> 2, cq = t & 3;
    float tot[2];
#pragma unroll
    for (int half = 0; half < 2; ++half) {
      float r[8];
#pragma unroll
      for (int j = 0; j < 8; ++j) r[j] = accsF[half][j][h4][cq];
      tot[half] = __fadd_rn(__fadd_rn(__fadd_rn(r[0], r[1]), __fadd_rn(r[2], r[3])),
                            __fadd_rn(__fadd_rn(r[4], r[5]), __fadd_rn(r[6], r[7])));
    }
    znorm[b * 1024 + hw0 + t] = __fadd_rn(tot[0], tot[1]);
  }

  // write phase: thread -> row hww, 64 c's
  const int hww = t >> 2, cqq = (t & 3) * 64;
  size_t obase = ((size_t)(b * 1024 + hw0 + hww)) * 256 + cqq;
#pragma unroll
  for (int v = 0; v < 8; ++v) {
    ushort8 oh, ol;
#pragma unroll
    for (int j = 0; j < 8; ++j) {
      oh[j] = T16[hww][cqq + v * 8 + j];
      ol[j] = Tlo[hww][cqq + v * 8 + j];
    }
    *reinterpret_cast<ushort8*>(zhi + obase + v * 8) = oh;
    *reinterpret_cast<ushort8*>(zlo + obase + v * 8) = ol;
  }
}

// ---------------------------------------------------------------------------
// Tiled 3-product split-bf16 MFMA argmin, v3:
//  * XCD-bijective swizzle (round 5: FETCH 168->21 MB, keep)
//  * BK=32, double-buffered 32KB LDS total -> 4 blocks/CU (was 2):
//    24 segments x {prefetch(s+1) -> 16 MFMA -> 1 barrier}; occupancy-driven
//    latency hiding replaces the exposed vmcnt drain (round-5 diagnosis)
//  * 64B-row XOR swizzle (((row>>1)&3)<<4): round-2 layout, measured 0
//    bank conflicts
// Numerics identical: dot = zhi.ehi + zhi.elo + zlo.ehi, fp32 MFMA acc.
__global__ __launch_bounds__(256) void argmin_tile(
    const unsigned short* __restrict__ zhi, const unsigned short* __restrict__ zlo,
    const unsigned short* __restrict__ ehi, const unsigned short* __restrict__ elo,
    const float* __restrict__ znorm, const float* __restrict__ enorm,
    float* __restrict__ pbd, int* __restrict__ pbi, float* __restrict__ pb2) {
  __shared__ __align__(16) char As[2][8192];
  __shared__ __align__(16) char Bs[2][8192];

  const int tid = threadIdx.x;
  const int lane = tid & 63, w = tid >> 6;
  const int wr = w >> 1, wc = w & 1;
  const int l15 = lane & 15, g = lane >> 4;

  // XCD swizzle: xcd = bid&7 (HW round-robin); 32 row-panels x 8 e-tiles/XCD
  const int bid = blockIdx.x;
  const int nb = (bid >> 3) & 7;
  const int mb = (bid & 7) * 32 + (bid >> 6);
  const int n0 = mb * 128;
  const int e0 = nb * 128;

  float znr[4][4];
#pragma unroll
  for (int mi = 0; mi < 4; ++mi)
#pragma unroll
    for (int rg = 0; rg < 4; ++rg)
      znr[mi][rg] = znorm[n0 + wr * 64 + mi * 16 + g * 4 + rg];

  // staging offsets: 128 rows x 32 k bf16 (8KB tile), 64B rows,
  // XOR swizzle (((row>>1)&3)<<4), source pre-swizzled (rule 21)
  int ldsoff[2], grow[2], gcol[2];
#pragma unroll
  for (int i = 0; i < 2; ++i) {
    int off = i * 4096 + tid * 16;
    int row = off >> 6, cb = off & 63;
    int csb = cb ^ (((row >> 1) & 3) << 4);
    ldsoff[i] = off; grow[i] = row; gcol[i] = csb >> 1;
  }

#define STAGE(SRC, DST, ROWBASE, KELEM)                                        \
  {                                                                            \
    _Pragma("unroll")                                                          \
    for (int i = 0; i < 2; ++i)                                                \
      gl_lds16(SRC + (size_t)((ROWBASE) + grow[i]) * 256 + (KELEM) + gcol[i],  \
               DST + ldsoff[i]);                                               \
  }

  f32x4 acc[4][4];
  const f32x4 z4 = {0.f, 0.f, 0.f, 0.f};
#pragma unroll
  for (int mi = 0; mi < 4; ++mi)
#pragma unroll
    for (int nj = 0; nj < 4; ++nj) acc[mi][nj] = z4;

  // 24 segments: pass p = s>>3 (0: zhi.ehi, 1: zhi.elo, 2: zlo.ehi), kt = s&7
  STAGE(zhi, As[0], n0, 0);
  STAGE(ehi, Bs[0], e0, 0);
  __syncthreads();

  int buf = 0;
  for (int s = 0; s < 24; ++s) {
    if (s + 1 < 24) {
      const int sn = s + 1, pn = sn >> 3, kn = (sn & 7) * 32;
      const unsigned short* An = (pn < 2) ? zhi : zlo;
      const unsigned short* Bn = (pn == 1) ? elo : ehi;
      STAGE(An, As[buf ^ 1], n0, kn);
      STAGE(Bn, Bs[buf ^ 1], e0, kn);
    }
    bf16x8 af[4], bv[4];
#pragma unroll
    for (int mi = 0; mi < 4; ++mi) {
      int rr = wr * 64 + mi * 16 + l15;
      int cc = (g * 16) ^ (((rr >> 1) & 3) << 4);
      af[mi] = *reinterpret_cast<const bf16x8*>(&As[buf][rr * 64 + cc]);
    }
#pragma unroll
    for (int nj = 0; nj < 4; ++nj) {
      int er = wc * 64 + nj * 16 + l15;
      int cc = (g * 16) ^ (((er >> 1) & 3) << 4);
      bv[nj] = *reinterpret_cast<const bf16x8*>(&Bs[buf][er * 64 + cc]);
    }
#pragma unroll
    for (int mi = 0; mi < 4; ++mi)
#pragma unroll
      for (int nj = 0; nj < 4; ++nj)
        acc[mi][nj] = __builtin_amdgcn_mfma_f32_16x16x32_bf16(af[mi], bv[nj], acc[mi][nj], 0, 0, 0);
    __syncthreads();   // drains prefetch vmcnt + guards buffer reuse
    buf ^= 1;
  }

  // epilogue: d = fmaf(-2, dot, zn+en), top-2 within this 128-e tile
  float bestd[4][4], b2d[4][4]; int besti[4][4];
#pragma unroll
  for (int mi = 0; mi < 4; ++mi)
#pragma unroll
    for (int rg = 0; rg < 4; ++rg) { bestd[mi][rg] = 3.4e38f; b2d[mi][rg] = 3.4e38f; besti[mi][rg] = 0; }

#pragma unroll
  for (int nj = 0; nj < 4; ++nj) {
    int e = e0 + wc * 64 + nj * 16 + l15;
    float en = enorm[e];
#pragma unroll
    for (int mi = 0; mi < 4; ++mi)
#pragma unroll
      for (int rg = 0; rg < 4; ++rg) {
        float d = fmaf(-2.0f, acc[mi][nj][rg], __fadd_rn(znr[mi][rg], en));
        if (d < bestd[mi][rg]) {
          b2d[mi][rg] = bestd[mi][rg]; bestd[mi][rg] = d; besti[mi][rg] = e;
        } else if (d < b2d[mi][rg]) {
          b2d[mi][rg] = d;
        }
      }
  }

  float* redd = reinterpret_cast<float*>(&As[0][0]);
  int*   redi = reinterpret_cast<int*>(&As[0][0] + 1024);
  float* red2 = reinterpret_cast<float*>(&As[0][0] + 2048);

#pragma unroll
  for (int mi = 0; mi < 4; ++mi)
#pragma unroll
    for (int rg = 0; rg < 4; ++rg) {
      float bd = bestd[mi][rg]; int bi = besti[mi][rg]; float b2 = b2d[mi][rg];
#pragma unroll
      for (int m = 1; m < 16; m <<= 1) {
        float od = __shfl_xor(bd, m, 64);
        int   oi = __shfl_xor(bi, m, 64);
        float o2 = __shfl_xor(b2, m, 64);
        float hi = fmaxf(bd, od);
        b2 = fminf(fminf(b2, o2), hi);
        if (od < bd || (od == bd && oi < bi)) { bd = od; bi = oi; }
      }
      if (l15 == 0) {
        int lr = wr * 64 + mi * 16 + g * 4 + rg;
        redd[lr * 2 + wc] = bd; redi[lr * 2 + wc] = bi; red2[lr * 2 + wc] = b2;
      }
    }
  __syncthreads();

  if (tid < 128) {
    float d0 = redd[tid * 2], d1 = redd[tid * 2 + 1];
    int   i0 = redi[tid * 2], i1 = redi[tid * 2 + 1];
    float s0 = red2[tid * 2], s1 = red2[tid * 2 + 1];
    float bd; int bi;
    if (d1 < d0 || (d1 == d0 && i1 < i0)) { bd = d1; bi = i1; } else { bd = d0; bi = i0; }
    float b2 = fminf(fminf(s0, s1), fmaxf(d0, d1));
    size_t o = (size_t)(n0 + tid) * 8 + nb;
    pbd[o] = bd; pbi[o] = bi; pb2[o] = b2;
  }
#undef STAGE
}

// ---------------------------------------------------------------------------
// merge 8 per-block top-2 candidates per row; exact first-index tie-break
__global__ __launch_bounds__(256) void merge_kernel(
    const float* __restrict__ pbd, const int* __restrict__ pbi,
    const float* __restrict__ pb2,
    int* __restrict__ idx_out, float* __restrict__ loss_part,
    int* __restrict__ flag_cnt, int* __restrict__ flag_list) {
  int n = blockIdx.x * 256 + threadIdx.x;
  float bd = 3.4e38f; int bi = 0x7FFFFFFF; int bnb = -1;
#pragma unroll
  for (int nb = 0; nb < 8; ++nb) {
    float d = pbd[(size_t)n * 8 + nb];
    int   i = pbi[(size_t)n * 8 + nb];
    if (d < bd || (d == bd && i < bi)) { bd = d; bi = i; bnb = nb; }
  }
  float b2 = 3.4e38f;
#pragma unroll
  for (int nb = 0; nb < 8; ++nb) {
    float v = (nb == bnb) ? pb2[(size_t)n * 8 + nb] : pbd[(size_t)n * 8 + nb];
    b2 = fminf(b2, v);
  }
  idx_out[n] = bi;
  loss_part[n] = bd;
  if (b2 - bd < THETA) {
    int p = atomicAdd(flag_cnt, 1);
    flag_list[p] = n;
  }
}

// ---------------------------------------------------------------------------
// coalesced exact-fp32 repair (round-1-certified arithmetic)
__global__ __launch_bounds__(256) void repair_kernel(
    const float* __restrict__ z, const float* __restrict__ embT,
    const float* __restrict__ znorm, const float* __restrict__ enorm,
    const int* __restrict__ flag_cnt, const int* __restrict__ flag_list,
    int* __restrict__ idx_out) {
  __shared__ float zrow[256];
  __shared__ float rd[256];
  __shared__ int   ri[256];
  const int t = threadIdx.x;
  const int cnt = flag_cnt[0] < NROWS ? flag_cnt[0] : NROWS;
  const float4* embT4 = reinterpret_cast<const float4*>(embT);
  for (int j = blockIdx.x; j < cnt; j += gridDim.x) {
    const int n = flag_list[j];
    __syncthreads();
    zrow[t] = z[(size_t)(n >> 10) * ZB_STRIDE + (size_t)t * 1024 + (n & 1023)];
    __syncthreads();
    const float zn = znorm[n];
    float4 dot = {0.f, 0.f, 0.f, 0.f};
    for (int k = 0; k < 256; ++k) {
      float4 v = embT4[k * 256 + t];
      float s = zrow[k];
      dot.x = fmaf(s, v.x, dot.x);
      dot.y = fmaf(s, v.y, dot.y);
      dot.z = fmaf(s, v.z, dot.z);
      dot.w = fmaf(s, v.w, dot.w);
    }
    float bd = 3.4e38f; int bi = 0;
    const float dv[4] = {dot.x, dot.y, dot.z, dot.w};
#pragma unroll
    for (int q = 0; q < 4; ++q) {
      int e = t * 4 + q;
      float d = __fsub_rn(__fadd_rn(zn, enorm[e]), __fmul_rn(2.0f, dv[q]));
      if (d < bd) { bd = d; bi = e; }
    }
    rd[t] = bd; ri[t] = bi;
    __syncthreads();
    for (int s2 = 128; s2 > 0; s2 >>= 1) {
      if (t < s2) {
        float od = rd[t + s2]; int oi = ri[t + s2];
        if (od < rd[t] || (od == rd[t] && oi < ri[t])) { rd[t] = od; ri[t] = oi; }
      }
      __syncthreads();
    }
    if (t == 0) idx_out[n] = ri[0];
  }
}

// ---------------------------------------------------------------------------
__global__ __launch_bounds__(256) void onehot_kernel(const int* __restrict__ idx,
                                                     float* __restrict__ out_enc) {
  for (int i = blockIdx.x * 256 + threadIdx.x; i < NROWS * 256; i += 2048 * 256) {
    int n = i >> 8, j4 = i & 255;
    int e = idx[n];
    float4 v = {0.f, 0.f, 0.f, 0.f};
    if ((e >> 2) == j4) ((float*)&v)[e & 3] = 1.0f;
    reinterpret_cast<float4*>(out_enc)[i] = v;
  }
}

__global__ __launch_bounds__(256) void idxf_hist_kernel(const int* __restrict__ idx,
                                                        float* __restrict__ out_idxf,
                                                        int* __restrict__ hist) {
  int n = blockIdx.x * 256 + threadIdx.x;
  int e = idx[n];
  out_idxf[n] = (float)e;
  atomicAdd(&hist[e], 1);
}

__global__ __launch_bounds__(256) void gather_kernel(const float* __restrict__ emb,
                                                     const int* __restrict__ idx,
                                                     float* __restrict__ zq_out) {
  int bh = blockIdx.x;
  int b = bh >> 5, h = bh & 31;
  int t = threadIdx.x;
  int ww = t & 31;
  int gg = t >> 5;
  int n = b * 1024 + h * 32 + ww;
  int e = idx[n];
  const float* eb = emb + (size_t)e * CDIM;
  float* ob = zq_out + (size_t)b * ZB_STRIDE + h * 32 + ww;
#pragma unroll
  for (int u = 0; u < 32; ++u) {
    int c = gg * 32 + u;
    ob[(size_t)c * 1024] = eb[c];
  }
}

__global__ __launch_bounds__(256) void finalize_kernel(const float* __restrict__ loss_part,
                                                       const int* __restrict__ hist,
                                                       float* __restrict__ out_loss,
                                                       float* __restrict__ out_perp) {
  __shared__ float red[256];
  int t = threadIdx.x;
  float sum = 0.f;
  for (int i = t; i < NROWS; i += 256) sum += loss_part[i];
  red[t] = sum;
  __syncthreads();
  for (int s2 = 128; s2 > 0; s2 >>= 1) {
    if (t < s2) red[t] += red[t + s2];
    __syncthreads();
  }
  if (t == 0) out_loss[0] = 1.25f * (red[0] / 8388608.0f);
  __syncthreads();
  float hs = 0.f;
  for (int i = t; i < 1024; i += 256) {
    float em = (float)hist[i] / 32768.0f;
    hs += em * logf(em + 1e-10f);
  }
  red[t] = hs;
  __syncthreads();
  for (int s2 = 128; s2 > 0; s2 >>= 1) {
    if (t < s2) red[t] += red[t + s2];
    __syncthreads();
  }
  if (t == 0) out_perp[0] = expf(-red[0]);
}

// ---------------------------------------------------------------------------
extern "C" void kernel_launch(void* const* d_in, const int* in_sizes, int n_in,
                              void* d_out, int out_size, void* d_ws, size_t ws_size,
                              hipStream_t stream) {
  const float* z   = (const float*)d_in[0];
  const float* emb = (const float*)d_in[1];
  float* out = (float*)d_out;

  float* out_zq   = out + ZQ_OFF;
  float* out_loss = out + LOSS_OFF;
  float* out_perp = out + PERP_OFF;
  float* out_enc  = out + ENC_OFF;
  float* out_idxf = out + IDX_OFF;

  // workspace (small)
  int*   idx       = (int*)d_ws;                   // 32768
  int*   hist      = idx + NROWS;                  // 1024
  int*   flag_cnt  = hist + NE;                    // 4 (1 used)
  int*   flag_list = flag_cnt + 4;                 // 32768
  float* loss_part = (float*)(flag_list + NROWS);  // 32768
  float* znorm     = loss_part + NROWS;            // 32768
  float* enorm     = znorm + NROWS;                // 1024

  // staging buffers carved from the one-hot output region (overwritten later)
  unsigned short* zhi  = (unsigned short*)(out_enc + 2);   // 8388608 u16 (16B-aligned)
  unsigned short* ehi  = zhi + (size_t)NROWS * CDIM;       // 262144
  unsigned short* zlo  = ehi + (size_t)NE * CDIM;          // 8388608
  unsigned short* elo  = zlo + (size_t)NROWS * CDIM;       // 262144
  float*          embT = (float*)(elo + (size_t)NE * CDIM);// 262144 f32
  float*          pbd  = embT + 262144;                    // 262144 f32
  int*            pbi  = (int*)(pbd + 262144);             // 262144 i32
  float*          pb2  = (float*)(pbi + 262144);           // 262144 f32

  // hist (NE ints) and flag_cnt (adjacent) in one memset
  hipMemsetAsync(hist, 0, (NE + 1) * sizeof(int), stream);

  convert_z_kernel<<<512, 256, 0, stream>>>(z, zhi, zlo, znorm);
  convert_e_kernel<<<128, 256, 0, stream>>>(emb, ehi, elo);
  enorm_kernel<<<NE / 256, 256, 0, stream>>>(emb, enorm);
  transpose_e_kernel<<<256, 256, 0, stream>>>(emb, embT);
  argmin_tile<<<2048, 256, 0, stream>>>(zhi, zlo, ehi, elo, znorm, enorm, pbd, pbi, pb2);
  merge_kernel<<<NROWS / 256, 256, 0, stream>>>(pbd, pbi, pb2, idx, loss_part, flag_cnt, flag_list);
  repair_kernel<<<1024, 256, 0, stream>>>(z, embT, znorm, enorm, flag_cnt, flag_list, idx);
  onehot_kernel<<<2048, 256, 0, stream>>>(idx, out_enc);
  idxf_hist_kernel<<<NROWS / 256, 256, 0, stream>>>(idx, out_idxf, hist);
  gather_kernel<<<1024, 256, 0, stream>>>(emb, idx, out_zq);
  finalize_kernel<<<1, 256, 0, stream>>>(loss_part, hist, out_loss, out_perp);
}

// Round 7
// 267.908 us; speedup vs baseline: 1.1090x; 1.1090x over previous
//
#include <hip/hip_runtime.h>
#include <math.h>

#define NROWS 32768
#define NE    1024
#define CDIM  256
#define ZB_STRIDE 262144

#define ZQ_OFF   0
#define LOSS_OFF 8388608
#define PERP_OFF 8388609
#define ENC_OFF  8388610
#define IDX_OFF  41943042

#define THETA 1.0e-4f

typedef __attribute__((ext_vector_type(8))) short bf16x8;
typedef __attribute__((ext_vector_type(4))) float f32x4;
typedef __attribute__((ext_vector_type(8))) unsigned short ushort8;

// RNE float -> bf16 bits
__device__ __forceinline__ unsigned short f2bf(float f) {
  union { float f; unsigned u; } v; v.f = f;
  unsigned r = v.u + 0x7FFFu + ((v.u >> 16) & 1u);
  return (unsigned short)(r >> 16);
}
__device__ __forceinline__ float bf2f(unsigned short b) {
  union { float f; unsigned u; } v; v.u = ((unsigned)b) << 16;
  return v.f;
}

// async global->LDS, 16B per lane
__device__ __forceinline__ void gl_lds16(const unsigned short* g, char* l) {
  __builtin_amdgcn_global_load_lds(
      (const __attribute__((address_space(1))) unsigned short*)g,
      (__attribute__((address_space(3))) char*)l, 16, 0, 0);
}

// ---------------------------------------------------------------------------
// numpy-pairwise-exact sum of squares (stride 1)
__device__ __forceinline__ float np_sumsq_256_s1(const float* __restrict__ base) {
  float tot[2];
#pragma unroll
  for (int hh = 0; hh < 2; ++hh) {
    float r[8];
#pragma unroll
    for (int j = 0; j < 8; ++j) {
      float x = base[hh * 128 + j];
      r[j] = __fmul_rn(x, x);
    }
    for (int i = 8; i < 128; i += 8) {
#pragma unroll
      for (int j = 0; j < 8; ++j) {
        float x = base[hh * 128 + i + j];
        r[j] = __fadd_rn(r[j], __fmul_rn(x, x));
      }
    }
    tot[hh] = __fadd_rn(__fadd_rn(__fadd_rn(r[0], r[1]), __fadd_rn(r[2], r[3])),
                        __fadd_rn(__fadd_rn(r[4], r[5]), __fadd_rn(r[6], r[7])));
  }
  return __fadd_rn(tot[0], tot[1]);
}

__global__ __launch_bounds__(256) void enorm_kernel(const float* __restrict__ emb,
                                                    float* __restrict__ enorm) {
  int n = blockIdx.x * 256 + threadIdx.x;
  enorm[n] = np_sumsq_256_s1(emb + (size_t)n * CDIM);
}

// emb fp32 -> bf16 hi + lo
__global__ __launch_bounds__(256) void convert_e_kernel(const float* __restrict__ emb,
                                                        unsigned short* __restrict__ ehi,
                                                        unsigned short* __restrict__ elo) {
  int i = (blockIdx.x * 256 + threadIdx.x) * 8;
  ushort8 oh, ol;
#pragma unroll
  for (int j = 0; j < 8; ++j) {
    float x = emb[i + j];
    unsigned short h = f2bf(x);
    oh[j] = h;
    ol[j] = f2bf(__fsub_rn(x, bf2f(h)));
  }
  *reinterpret_cast<ushort8*>(ehi + i) = oh;
  *reinterpret_cast<ushort8*>(elo + i) = ol;
}

// emb[e][c] -> embT[c][e] fp32 (for coalesced repair)
__global__ __launch_bounds__(256) void transpose_e_kernel(const float* __restrict__ emb,
                                                          float* __restrict__ embT) {
  __shared__ float tile[32][33];
  int be = blockIdx.x & 31, bc = blockIdx.x >> 5;
  int tx = threadIdx.x & 31, ty = threadIdx.x >> 5;
#pragma unroll
  for (int i = 0; i < 4; ++i)
    tile[ty + 8 * i][tx] = emb[(size_t)(be * 32 + ty + 8 * i) * 256 + bc * 32 + tx];
  __syncthreads();
#pragma unroll
  for (int i = 0; i < 4; ++i)
    embT[(size_t)(bc * 32 + ty + 8 * i) * 1024 + be * 32 + tx] = tile[tx][ty + 8 * i];
}

// ---------------------------------------------------------------------------
// z (b,c,h,w) fp32 -> zhi,zlo (n,c) bf16 transpose + numpy-exact znorm.
__global__ __launch_bounds__(256) void convert_z_kernel(const float* __restrict__ z,
                                                        unsigned short* __restrict__ zhi,
                                                        unsigned short* __restrict__ zlo,
                                                        float* __restrict__ znorm) {
  __shared__ unsigned short T16[64][266];
  __shared__ unsigned short Tlo[64][266];
  __shared__ float accsF[2][8][16][4];
  const int t = threadIdx.x;
  const int b = blockIdx.x >> 4, hwt = blockIdx.x & 15;
  const int hw0 = hwt * 64;
  const int hw4 = t & 15;          // float4 unit within 64 hw
  const int jj = (t >> 4) & 7;     // np accumulator index
  const int hh = t >> 7;           // half
  const float* zb = z + (size_t)b * ZB_STRIDE + hw0 + hw4 * 4;

  float rr[4];
#pragma unroll
  for (int i = 0; i < 16; ++i) {
    int c = hh * 128 + jj + 8 * i;
    float4 v = *reinterpret_cast<const float4*>(zb + (size_t)c * 1024);
    const float xv[4] = {v.x, v.y, v.z, v.w};
#pragma unroll
    for (int q = 0; q < 4; ++q) {
      float p = __fmul_rn(xv[q], xv[q]);
      rr[q] = (i == 0) ? p : __fadd_rn(rr[q], p);
      unsigned short hbits = f2bf(xv[q]);
      T16[hw4 * 4 + q][c] = hbits;
      Tlo[hw4 * 4 + q][c] = f2bf(__fsub_rn(xv[q], bf2f(hbits)));
    }
  }
#pragma unroll
  for (int q = 0; q < 4; ++q) accsF[hh][jj][hw4][q] = rr[q];
  __syncthreads();

  if (t < 64) {
    const int h4 = t >> 2, cq = t & 3;
    float tot[2];
#pragma unroll
    for (int half = 0; half < 2; ++half) {
      float r[8];
#pragma unroll
      for (int j = 0; j < 8; ++j) r[j] = accsF[half][j][h4][cq];
      tot[half] = __fadd_rn(__fadd_rn(__fadd_rn(r[0], r[1]), __fadd_rn(r[2], r[3])),
                            __fadd_rn(__fadd_rn(r[4], r[5]), __fadd_rn(r[6], r[7])));
    }
    znorm[b * 1024 + hw0 + t] = __fadd_rn(tot[0], tot[1]);
  }

  // write phase: thread -> row hww, 64 c's
  const int hww = t >> 2, cqq = (t & 3) * 64;
  size_t obase = ((size_t)(b * 1024 + hw0 + hww)) * 256 + cqq;
#pragma unroll
  for (int v = 0; v < 8; ++v) {
    ushort8 oh, ol;
#pragma unroll
    for (int j = 0; j < 8; ++j) {
      oh[j] = T16[hww][cqq + v * 8 + j];
      ol[j] = Tlo[hww][cqq + v * 8 + j];
    }
    *reinterpret_cast<ushort8*>(zhi + obase + v * 8) = oh;
    *reinterpret_cast<ushort8*>(zlo + obase + v * 8) = ol;
  }
}

// ---------------------------------------------------------------------------
// Tiled 3-product split-bf16 MFMA argmin, v4:
//  * r5 geometry: BK=64, double-buffered 64KB LDS, 128B rows,
//    XOR swizzle ((row&7)<<4) -- measured 0 bank conflicts, FETCH 20.7MB
//  * T4 counted vmcnt: raw s_barrier + literal s_waitcnt vmcnt(8) -- the 8
//    next-tile global_load_lds stay IN FLIGHT across both barriers (r6
//    diagnosis: __syncthreads' vmcnt(0) drain serialized every segment)
//  * T5 setprio around MFMA cluster; sched_barrier(0) fences (rule 18)
// Numerics identical: dot = zhi.ehi + zhi.elo + zlo.ehi, fp32 MFMA acc.
__global__ __launch_bounds__(256) void argmin_tile(
    const unsigned short* __restrict__ zhi, const unsigned short* __restrict__ zlo,
    const unsigned short* __restrict__ ehi, const unsigned short* __restrict__ elo,
    const float* __restrict__ znorm, const float* __restrict__ enorm,
    float* __restrict__ pbd, int* __restrict__ pbi, float* __restrict__ pb2) {
  __shared__ __align__(16) char As[2][16384];
  __shared__ __align__(16) char Bs[2][16384];

  const int tid = threadIdx.x;
  const int lane = tid & 63, w = tid >> 6;
  const int wr = w >> 1, wc = w & 1;
  const int l15 = lane & 15, g = lane >> 4;

  // XCD swizzle: xcd = bid&7 (HW round-robin); 32 row-panels x 8 e-tiles/XCD
  const int bid = blockIdx.x;
  const int nb = (bid >> 3) & 7;
  const int mb = (bid & 7) * 32 + (bid >> 6);
  const int n0 = mb * 128;
  const int e0 = nb * 128;

  float znr[4][4];
#pragma unroll
  for (int mi = 0; mi < 4; ++mi)
#pragma unroll
    for (int rg = 0; rg < 4; ++rg)
      znr[mi][rg] = znorm[n0 + wr * 64 + mi * 16 + g * 4 + rg];

  // staging offsets: 128 rows x 64 k bf16 (16KB tile), 128B rows,
  // XOR swizzle ((row&7)<<4), source pre-swizzled (rule 21)
  int ldsoff[4], grow[4], gcol[4];
#pragma unroll
  for (int i = 0; i < 4; ++i) {
    int off = i * 4096 + tid * 16;
    int row = off >> 7, cb = off & 127;
    int csb = cb ^ ((row & 7) << 4);
    ldsoff[i] = off; grow[i] = row; gcol[i] = csb >> 1;
  }

#define STAGE(SRC, DST, ROWBASE, KELEM)                                        \
  {                                                                            \
    _Pragma("unroll")                                                          \
    for (int i = 0; i < 4; ++i)                                                \
      gl_lds16(SRC + (size_t)((ROWBASE) + grow[i]) * 256 + (KELEM) + gcol[i],  \
               DST + ldsoff[i]);                                               \
  }

  f32x4 acc[4][4];
  const f32x4 z4 = {0.f, 0.f, 0.f, 0.f};
#pragma unroll
  for (int mi = 0; mi < 4; ++mi)
#pragma unroll
    for (int nj = 0; nj < 4; ++nj) acc[mi][nj] = z4;

  // segment s (12 total, BK=64): A = zhi (s<8) | zlo; B = ehi | elo (4..7)
  STAGE(zhi, As[0], n0, 0);
  STAGE(ehi, Bs[0], e0, 0);

  int buf = 0;
#pragma unroll 1
  for (int s = 0; s < 12; ++s) {
    if (s < 11) {
      const int sn = s + 1;
      const unsigned short* An = (sn < 8) ? zhi : zlo;
      const unsigned short* Bn = (sn >= 4 && sn < 8) ? elo : ehi;
      const int kn = (sn & 3) * 64;
      STAGE(An, As[buf ^ 1], n0, kn);
      STAGE(Bn, Bs[buf ^ 1], e0, kn);
      // my 8 loads for buf[cur] complete; 8 next-tile loads stay in flight
      asm volatile("s_waitcnt vmcnt(8)" ::: "memory");
    } else {
      asm volatile("s_waitcnt vmcnt(0)" ::: "memory");
    }
    __builtin_amdgcn_s_barrier();          // all waves' cur-tile staged
    __builtin_amdgcn_sched_barrier(0);     // no ds_read hoisting above barrier
#pragma unroll
    for (int ks = 0; ks < 2; ++ks) {
      bf16x8 af[4], bv[4];
#pragma unroll
      for (int mi = 0; mi < 4; ++mi) {
        int rr = wr * 64 + mi * 16 + l15;
        int cc = (ks * 64 + g * 16) ^ ((rr & 7) << 4);
        af[mi] = *reinterpret_cast<const bf16x8*>(&As[buf][rr * 128 + cc]);
      }
#pragma unroll
      for (int nj = 0; nj < 4; ++nj) {
        int er = wc * 64 + nj * 16 + l15;
        int cc = (ks * 64 + g * 16) ^ ((er & 7) << 4);
        bv[nj] = *reinterpret_cast<const bf16x8*>(&Bs[buf][er * 128 + cc]);
      }
      __builtin_amdgcn_s_setprio(1);
#pragma unroll
      for (int mi = 0; mi < 4; ++mi)
#pragma unroll
        for (int nj = 0; nj < 4; ++nj)
          acc[mi][nj] = __builtin_amdgcn_mfma_f32_16x16x32_bf16(af[mi], bv[nj], acc[mi][nj], 0, 0, 0);
      __builtin_amdgcn_s_setprio(0);
    }
    __builtin_amdgcn_sched_barrier(0);     // no next-STAGE sinking above barrier
    __builtin_amdgcn_s_barrier();          // reads done before buf re-staged
    buf ^= 1;
  }

  // epilogue: d = fmaf(-2, dot, zn+en), top-2 within this 128-e tile
  float bestd[4][4], b2d[4][4]; int besti[4][4];
#pragma unroll
  for (int mi = 0; mi < 4; ++mi)
#pragma unroll
    for (int rg = 0; rg < 4; ++rg) { bestd[mi][rg] = 3.4e38f; b2d[mi][rg] = 3.4e38f; besti[mi][rg] = 0; }

#pragma unroll
  for (int nj = 0; nj < 4; ++nj) {
    int e = e0 + wc * 64 + nj * 16 + l15;
    float en = enorm[e];
#pragma unroll
    for (int mi = 0; mi < 4; ++mi)
#pragma unroll
      for (int rg = 0; rg < 4; ++rg) {
        float d = fmaf(-2.0f, acc[mi][nj][rg], __fadd_rn(znr[mi][rg], en));
        if (d < bestd[mi][rg]) {
          b2d[mi][rg] = bestd[mi][rg]; bestd[mi][rg] = d; besti[mi][rg] = e;
        } else if (d < b2d[mi][rg]) {
          b2d[mi][rg] = d;
        }
      }
  }

  float* redd = reinterpret_cast<float*>(&As[0][0]);
  int*   redi = reinterpret_cast<int*>(&As[0][0] + 1024);
  float* red2 = reinterpret_cast<float*>(&As[0][0] + 2048);

#pragma unroll
  for (int mi = 0; mi < 4; ++mi)
#pragma unroll
    for (int rg = 0; rg < 4; ++rg) {
      float bd = bestd[mi][rg]; int bi = besti[mi][rg]; float b2 = b2d[mi][rg];
#pragma unroll
      for (int m = 1; m < 16; m <<= 1) {
        float od = __shfl_xor(bd, m, 64);
        int   oi = __shfl_xor(bi, m, 64);
        float o2 = __shfl_xor(b2, m, 64);
        float hi = fmaxf(bd, od);
        b2 = fminf(fminf(b2, o2), hi);
        if (od < bd || (od == bd && oi < bi)) { bd = od; bi = oi; }
      }
      if (l15 == 0) {
        int lr = wr * 64 + mi * 16 + g * 4 + rg;
        redd[lr * 2 + wc] = bd; redi[lr * 2 + wc] = bi; red2[lr * 2 + wc] = b2;
      }
    }
  __syncthreads();

  if (tid < 128) {
    float d0 = redd[tid * 2], d1 = redd[tid * 2 + 1];
    int   i0 = redi[tid * 2], i1 = redi[tid * 2 + 1];
    float s0 = red2[tid * 2], s1 = red2[tid * 2 + 1];
    float bd; int bi;
    if (d1 < d0 || (d1 == d0 && i1 < i0)) { bd = d1; bi = i1; } else { bd = d0; bi = i0; }
    float b2 = fminf(fminf(s0, s1), fmaxf(d0, d1));
    size_t o = (size_t)(n0 + tid) * 8 + nb;
    pbd[o] = bd; pbi[o] = bi; pb2[o] = b2;
  }
#undef STAGE
}

// ---------------------------------------------------------------------------
// merge 8 per-block top-2 candidates per row; exact first-index tie-break
__global__ __launch_bounds__(256) void merge_kernel(
    const float* __restrict__ pbd, const int* __restrict__ pbi,
    const float* __restrict__ pb2,
    int* __restrict__ idx_out, float* __restrict__ loss_part,
    int* __restrict__ flag_cnt, int* __restrict__ flag_list) {
  int n = blockIdx.x * 256 + threadIdx.x;
  float bd = 3.4e38f; int bi = 0x7FFFFFFF; int bnb = -1;
#pragma unroll
  for (int nb = 0; nb < 8; ++nb) {
    float d = pbd[(size_t)n * 8 + nb];
    int   i = pbi[(size_t)n * 8 + nb];
    if (d < bd || (d == bd && i < bi)) { bd = d; bi = i; bnb = nb; }
  }
  float b2 = 3.4e38f;
#pragma unroll
  for (int nb = 0; nb < 8; ++nb) {
    float v = (nb == bnb) ? pb2[(size_t)n * 8 + nb] : pbd[(size_t)n * 8 + nb];
    b2 = fminf(b2, v);
  }
  idx_out[n] = bi;
  loss_part[n] = bd;
  if (b2 - bd < THETA) {
    int p = atomicAdd(flag_cnt, 1);
    flag_list[p] = n;
  }
}

// ---------------------------------------------------------------------------
// coalesced exact-fp32 repair (round-1-certified arithmetic)
__global__ __launch_bounds__(256) void repair_kernel(
    const float* __restrict__ z, const float* __restrict__ embT,
    const float* __restrict__ znorm, const float* __restrict__ enorm,
    const int* __restrict__ flag_cnt, const int* __restrict__ flag_list,
    int* __restrict__ idx_out) {
  __shared__ float zrow[256];
  __shared__ float rd[256];
  __shared__ int   ri[256];
  const int t = threadIdx.x;
  const int cnt = flag_cnt[0] < NROWS ? flag_cnt[0] : NROWS;
  const float4* embT4 = reinterpret_cast<const float4*>(embT);
  for (int j = blockIdx.x; j < cnt; j += gridDim.x) {
    const int n = flag_list[j];
    __syncthreads();
    zrow[t] = z[(size_t)(n >> 10) * ZB_STRIDE + (size_t)t * 1024 + (n & 1023)];
    __syncthreads();
    const float zn = znorm[n];
    float4 dot = {0.f, 0.f, 0.f, 0.f};
    for (int k = 0; k < 256; ++k) {
      float4 v = embT4[k * 256 + t];
      float s = zrow[k];
      dot.x = fmaf(s, v.x, dot.x);
      dot.y = fmaf(s, v.y, dot.y);
      dot.z = fmaf(s, v.z, dot.z);
      dot.w = fmaf(s, v.w, dot.w);
    }
    float bd = 3.4e38f; int bi = 0;
    const float dv[4] = {dot.x, dot.y, dot.z, dot.w};
#pragma unroll
    for (int q = 0; q < 4; ++q) {
      int e = t * 4 + q;
      float d = __fsub_rn(__fadd_rn(zn, enorm[e]), __fmul_rn(2.0f, dv[q]));
      if (d < bd) { bd = d; bi = e; }
    }
    rd[t] = bd; ri[t] = bi;
    __syncthreads();
    for (int s2 = 128; s2 > 0; s2 >>= 1) {
      if (t < s2) {
        float od = rd[t + s2]; int oi = ri[t + s2];
        if (od < rd[t] || (od == rd[t] && oi < ri[t])) { rd[t] = od; ri[t] = oi; }
      }
      __syncthreads();
    }
    if (t == 0) idx_out[n] = ri[0];
  }
}

// ---------------------------------------------------------------------------
__global__ __launch_bounds__(256) void onehot_kernel(const int* __restrict__ idx,
                                                     float* __restrict__ out_enc) {
  for (int i = blockIdx.x * 256 + threadIdx.x; i < NROWS * 256; i += 2048 * 256) {
    int n = i >> 8, j4 = i & 255;
    int e = idx[n];
    float4 v = {0.f, 0.f, 0.f, 0.f};
    if ((e >> 2) == j4) ((float*)&v)[e & 3] = 1.0f;
    reinterpret_cast<float4*>(out_enc)[i] = v;
  }
}

__global__ __launch_bounds__(256) void idxf_hist_kernel(const int* __restrict__ idx,
                                                        float* __restrict__ out_idxf,
                                                        int* __restrict__ hist) {
  int n = blockIdx.x * 256 + threadIdx.x;
  int e = idx[n];
  out_idxf[n] = (float)e;
  atomicAdd(&hist[e], 1);
}

__global__ __launch_bounds__(256) void gather_kernel(const float* __restrict__ emb,
                                                     const int* __restrict__ idx,
                                                     float* __restrict__ zq_out) {
  int bh = blockIdx.x;
  int b = bh >> 5, h = bh & 31;
  int t = threadIdx.x;
  int ww = t & 31;
  int gg = t >> 5;
  int n = b * 1024 + h * 32 + ww;
  int e = idx[n];
  const float* eb = emb + (size_t)e * CDIM;
  float* ob = zq_out + (size_t)b * ZB_STRIDE + h * 32 + ww;
#pragma unroll
  for (int u = 0; u < 32; ++u) {
    int c = gg * 32 + u;
    ob[(size_t)c * 1024] = eb[c];
  }
}

__global__ __launch_bounds__(256) void finalize_kernel(const float* __restrict__ loss_part,
                                                       const int* __restrict__ hist,
                                                       float* __restrict__ out_loss,
                                                       float* __restrict__ out_perp) {
  __shared__ float red[256];
  int t = threadIdx.x;
  float sum = 0.f;
  for (int i = t; i < NROWS; i += 256) sum += loss_part[i];
  red[t] = sum;
  __syncthreads();
  for (int s2 = 128; s2 > 0; s2 >>= 1) {
    if (t < s2) red[t] += red[t + s2];
    __syncthreads();
  }
  if (t == 0) out_loss[0] = 1.25f * (red[0] / 8388608.0f);
  __syncthreads();
  float hs = 0.f;
  for (int i = t; i < 1024; i += 256) {
    float em = (float)hist[i] / 32768.0f;
    hs += em * logf(em + 1e-10f);
  }
  red[t] = hs;
  __syncthreads();
  for (int s2 = 128; s2 > 0; s2 >>= 1) {
    if (t < s2) red[t] += red[t + s2];
    __syncthreads();
  }
  if (t == 0) out_perp[0] = expf(-red[0]);
}

// ---------------------------------------------------------------------------
extern "C" void kernel_launch(void* const* d_in, const int* in_sizes, int n_in,
                              void* d_out, int out_size, void* d_ws, size_t ws_size,
                              hipStream_t stream) {
  const float* z   = (const float*)d_in[0];
  const float* emb = (const float*)d_in[1];
  float* out = (float*)d_out;

  float* out_zq   = out + ZQ_OFF;
  float* out_loss = out + LOSS_OFF;
  float* out_perp = out + PERP_OFF;
  float* out_enc  = out + ENC_OFF;
  float* out_idxf = out + IDX_OFF;

  // workspace (small)
  int*   idx       = (int*)d_ws;                   // 32768
  int*   hist      = idx + NROWS;                  // 1024
  int*   flag_cnt  = hist + NE;                    // 4 (1 used)
  int*   flag_list = flag_cnt + 4;                 // 32768
  float* loss_part = (float*)(flag_list + NROWS);  // 32768
  float* znorm     = loss_part + NROWS;            // 32768
  float* enorm     = znorm + NROWS;                // 1024

  // staging buffers carved from the one-hot output region (overwritten later)
  unsigned short* zhi  = (unsigned short*)(out_enc + 2);   // 8388608 u16 (16B-aligned)
  unsigned short* ehi  = zhi + (size_t)NROWS * CDIM;       // 262144
  unsigned short* zlo  = ehi + (size_t)NE * CDIM;          // 8388608
  unsigned short* elo  = zlo + (size_t)NROWS * CDIM;       // 262144
  float*          embT = (float*)(elo + (size_t)NE * CDIM);// 262144 f32
  float*          pbd  = embT + 262144;                    // 262144 f32
  int*            pbi  = (int*)(pbd + 262144);             // 262144 i32
  float*          pb2  = (float*)(pbi + 262144);           // 262144 f32

  // hist (NE ints) and flag_cnt (adjacent) in one memset
  hipMemsetAsync(hist, 0, (NE + 1) * sizeof(int), stream);

  convert_z_kernel<<<512, 256, 0, stream>>>(z, zhi, zlo, znorm);
  convert_e_kernel<<<128, 256, 0, stream>>>(emb, ehi, elo);
  enorm_kernel<<<NE / 256, 256, 0, stream>>>(emb, enorm);
  transpose_e_kernel<<<256, 256, 0, stream>>>(emb, embT);
  argmin_tile<<<2048, 256, 0, stream>>>(zhi, zlo, ehi, elo, znorm, enorm, pbd, pbi, pb2);
  merge_kernel<<<NROWS / 256, 256, 0, stream>>>(pbd, pbi, pb2, idx, loss_part, flag_cnt, flag_list);
  repair_kernel<<<1024, 256, 0, stream>>>(z, embT, znorm, enorm, flag_cnt, flag_list, idx);
  onehot_kernel<<<2048, 256, 0, stream>>>(idx, out_enc);
  idxf_hist_kernel<<<NROWS / 256, 256, 0, stream>>>(idx, out_idxf, hist);
  gather_kernel<<<1024, 256, 0, stream>>>(emb, idx, out_zq);
  finalize_kernel<<<1, 256, 0, stream>>>(loss_part, hist, out_loss, out_perp);
}

// Round 8
// 221.648 us; speedup vs baseline: 1.3405x; 1.2087x over previous
//
#include <hip/hip_runtime.h>
#include <math.h>

#define NROWS 32768
#define NE    1024
#define CDIM  256
#define ZB_STRIDE 262144

#define ZQ_OFF   0
#define LOSS_OFF 8388608
#define PERP_OFF 8388609
#define ENC_OFF  8388610
#define IDX_OFF  41943042

#define THETA 1.0e-4f
// e scaled by 2^12 before fp16 conversion; -2*dot = -2^-11 * acc
#define NEG2_SCALE (-0.00048828125f)

typedef _Float16 f16x8 __attribute__((ext_vector_type(8)));
typedef __attribute__((ext_vector_type(4))) float f32x4;
typedef __attribute__((ext_vector_type(8))) unsigned short ushort8;

// RNE float -> fp16 bits
__device__ __forceinline__ unsigned short f2h(float x) {
  _Float16 h = (_Float16)x;
  unsigned short u;
  __builtin_memcpy(&u, &h, 2);
  return u;
}

// async global->LDS, 16B per lane
__device__ __forceinline__ void gl_lds16(const unsigned short* g, char* l) {
  __builtin_amdgcn_global_load_lds(
      (const __attribute__((address_space(1))) unsigned short*)g,
      (__attribute__((address_space(3))) char*)l, 16, 0, 0);
}

// ---------------------------------------------------------------------------
// numpy-pairwise-exact sum of squares (stride 1)
__device__ __forceinline__ float np_sumsq_256_s1(const float* __restrict__ base) {
  float tot[2];
#pragma unroll
  for (int hh = 0; hh < 2; ++hh) {
    float r[8];
#pragma unroll
    for (int j = 0; j < 8; ++j) {
      float x = base[hh * 128 + j];
      r[j] = __fmul_rn(x, x);
    }
    for (int i = 8; i < 128; i += 8) {
#pragma unroll
      for (int j = 0; j < 8; ++j) {
        float x = base[hh * 128 + i + j];
        r[j] = __fadd_rn(r[j], __fmul_rn(x, x));
      }
    }
    tot[hh] = __fadd_rn(__fadd_rn(__fadd_rn(r[0], r[1]), __fadd_rn(r[2], r[3])),
                        __fadd_rn(__fadd_rn(r[4], r[5]), __fadd_rn(r[6], r[7])));
  }
  return __fadd_rn(tot[0], tot[1]);
}

__global__ __launch_bounds__(256) void enorm_kernel(const float* __restrict__ emb,
                                                    float* __restrict__ enorm) {
  int n = blockIdx.x * 256 + threadIdx.x;
  enorm[n] = np_sumsq_256_s1(emb + (size_t)n * CDIM);
}

// emb fp32 -> fp16 scaled by 2^12 (row-major unchanged)
__global__ __launch_bounds__(256) void convert_e_kernel(const float* __restrict__ emb,
                                                        unsigned short* __restrict__ ef16) {
  int i = (blockIdx.x * 256 + threadIdx.x) * 8;
  ushort8 o;
#pragma unroll
  for (int j = 0; j < 8; ++j) o[j] = f2h(emb[i + j] * 4096.0f);
  *reinterpret_cast<ushort8*>(ef16 + i) = o;
}

// emb[e][c] -> embT[c][e] fp32 (for coalesced repair)
__global__ __launch_bounds__(256) void transpose_e_kernel(const float* __restrict__ emb,
                                                          float* __restrict__ embT) {
  __shared__ float tile[32][33];
  int be = blockIdx.x & 31, bc = blockIdx.x >> 5;
  int tx = threadIdx.x & 31, ty = threadIdx.x >> 5;
#pragma unroll
  for (int i = 0; i < 4; ++i)
    tile[ty + 8 * i][tx] = emb[(size_t)(be * 32 + ty + 8 * i) * 256 + bc * 32 + tx];
  __syncthreads();
#pragma unroll
  for (int i = 0; i < 4; ++i)
    embT[(size_t)(bc * 32 + ty + 8 * i) * 1024 + be * 32 + tx] = tile[tx][ty + 8 * i];
}

// ---------------------------------------------------------------------------
// z (b,c,h,w) fp32 -> zf16 (n,c) fp16 transpose + numpy-exact znorm.
// (r4-verified accumulator tree, unchanged; only the lo-array dropped)
__global__ __launch_bounds__(256) void convert_z_kernel(const float* __restrict__ z,
                                                        unsigned short* __restrict__ zf16,
                                                        float* __restrict__ znorm) {
  __shared__ unsigned short T16[64][266];
  __shared__ float accsF[2][8][16][4];
  const int t = threadIdx.x;
  const int b = blockIdx.x >> 4, hwt = blockIdx.x & 15;
  const int hw0 = hwt * 64;
  const int hw4 = t & 15;          // float4 unit within 64 hw
  const int jj = (t >> 4) & 7;     // np accumulator index
  const int hh = t >> 7;           // half
  const float* zb = z + (size_t)b * ZB_STRIDE + hw0 + hw4 * 4;

  float rr[4];
#pragma unroll
  for (int i = 0; i < 16; ++i) {
    int c = hh * 128 + jj + 8 * i;
    float4 v = *reinterpret_cast<const float4*>(zb + (size_t)c * 1024);
    const float xv[4] = {v.x, v.y, v.z, v.w};
#pragma unroll
    for (int q = 0; q < 4; ++q) {
      float p = __fmul_rn(xv[q], xv[q]);
      rr[q] = (i == 0) ? p : __fadd_rn(rr[q], p);
      T16[hw4 * 4 + q][c] = f2h(xv[q]);
    }
  }
#pragma unroll
  for (int q = 0; q < 4; ++q) accsF[hh][jj][hw4][q] = rr[q];
  __syncthreads();

  if (t < 64) {
    const int h4 = t >> 2, cq = t & 3;
    float tot[2];
#pragma unroll
    for (int half = 0; half < 2; ++half) {
      float r[8];
#pragma unroll
      for (int j = 0; j < 8; ++j) r[j] = accsF[half][j][h4][cq];
      tot[half] = __fadd_rn(__fadd_rn(__fadd_rn(r[0], r[1]), __fadd_rn(r[2], r[3])),
                            __fadd_rn(__fadd_rn(r[4], r[5]), __fadd_rn(r[6], r[7])));
    }
    znorm[b * 1024 + hw0 + t] = __fadd_rn(tot[0], tot[1]);
  }

  // write phase: thread -> row hww, 64 c's
  const int hww = t >> 2, cqq = (t & 3) * 64;
  size_t obase = ((size_t)(b * 1024 + hw0 + hww)) * 256 + cqq;
#pragma unroll
  for (int v = 0; v < 8; ++v) {
    ushort8 o;
#pragma unroll
    for (int j = 0; j < 8; ++j) o[j] = T16[hww][cqq + v * 8 + j];
    *reinterpret_cast<ushort8*>(zf16 + obase + v * 8) = o;
  }
}

// ---------------------------------------------------------------------------
// Single-product fp16 MFMA argmin, v5:
//  * dot = sum fl16(z) * fl16(e*2^12); d = fmaf(-2^-11, acc, zn+en)
//    (sigma_d ~ 7e-6 = 0.23 ulp(256); unflagged rows np-safe at theta=1e-4)
//  * K=256 in 4 segments BK=64 -- LDS traffic / MFMA count / staging all
//    cut 3x vs the bf16-triple (r7 diagnosis: LDS-BW-bound at 2850 cyc/seg)
//  * r7 schedule kept: XCD-bijective swizzle, dbuf LDS, counted vmcnt(8),
//    setprio + sched_barrier fences, 0-conflict XOR swizzle ((row&7)<<4)
__global__ __launch_bounds__(256) void argmin_tile(
    const unsigned short* __restrict__ zf16, const unsigned short* __restrict__ ef16,
    const float* __restrict__ znorm, const float* __restrict__ enorm,
    float* __restrict__ pbd, int* __restrict__ pbi, float* __restrict__ pb2) {
  __shared__ __align__(16) char As[2][16384];
  __shared__ __align__(16) char Bs[2][16384];

  const int tid = threadIdx.x;
  const int lane = tid & 63, w = tid >> 6;
  const int wr = w >> 1, wc = w & 1;
  const int l15 = lane & 15, g = lane >> 4;

  // XCD swizzle: xcd = bid&7 (HW round-robin); 32 row-panels x 8 e-tiles/XCD
  const int bid = blockIdx.x;
  const int nb = (bid >> 3) & 7;
  const int mb = (bid & 7) * 32 + (bid >> 6);
  const int n0 = mb * 128;
  const int e0 = nb * 128;

  float znr[4][4];
#pragma unroll
  for (int mi = 0; mi < 4; ++mi)
#pragma unroll
    for (int rg = 0; rg < 4; ++rg)
      znr[mi][rg] = znorm[n0 + wr * 64 + mi * 16 + g * 4 + rg];

  // staging offsets: 128 rows x 64 k fp16 (16KB tile), 128B rows,
  // XOR swizzle ((row&7)<<4), source pre-swizzled (rule 21)
  int ldsoff[4], grow[4], gcol[4];
#pragma unroll
  for (int i = 0; i < 4; ++i) {
    int off = i * 4096 + tid * 16;
    int row = off >> 7, cb = off & 127;
    int csb = cb ^ ((row & 7) << 4);
    ldsoff[i] = off; grow[i] = row; gcol[i] = csb >> 1;
  }

#define STAGE(SRC, DST, ROWBASE, KELEM)                                        \
  {                                                                            \
    _Pragma("unroll")                                                          \
    for (int i = 0; i < 4; ++i)                                                \
      gl_lds16(SRC + (size_t)((ROWBASE) + grow[i]) * 256 + (KELEM) + gcol[i],  \
               DST + ldsoff[i]);                                               \
  }

  f32x4 acc[4][4];
  const f32x4 z4 = {0.f, 0.f, 0.f, 0.f};
#pragma unroll
  for (int mi = 0; mi < 4; ++mi)
#pragma unroll
    for (int nj = 0; nj < 4; ++nj) acc[mi][nj] = z4;

  // 4 segments, K chunk = s*64
  STAGE(zf16, As[0], n0, 0);
  STAGE(ef16, Bs[0], e0, 0);

  int buf = 0;
#pragma unroll 1
  for (int s = 0; s < 4; ++s) {
    if (s < 3) {
      const int kn = (s + 1) * 64;
      STAGE(zf16, As[buf ^ 1], n0, kn);
      STAGE(ef16, Bs[buf ^ 1], e0, kn);
      // my 8 loads for buf[cur] complete; 8 next-tile loads stay in flight
      asm volatile("s_waitcnt vmcnt(8)" ::: "memory");
    } else {
      asm volatile("s_waitcnt vmcnt(0)" ::: "memory");
    }
    __builtin_amdgcn_s_barrier();          // all waves' cur-tile staged
    __builtin_amdgcn_sched_barrier(0);     // no ds_read hoisting above barrier
#pragma unroll
    for (int ks = 0; ks < 2; ++ks) {
      f16x8 af[4], bv[4];
#pragma unroll
      for (int mi = 0; mi < 4; ++mi) {
        int rr = wr * 64 + mi * 16 + l15;
        int cc = (ks * 64 + g * 16) ^ ((rr & 7) << 4);
        af[mi] = *reinterpret_cast<const f16x8*>(&As[buf][rr * 128 + cc]);
      }
#pragma unroll
      for (int nj = 0; nj < 4; ++nj) {
        int er = wc * 64 + nj * 16 + l15;
        int cc = (ks * 64 + g * 16) ^ ((er & 7) << 4);
        bv[nj] = *reinterpret_cast<const f16x8*>(&Bs[buf][er * 128 + cc]);
      }
      __builtin_amdgcn_s_setprio(1);
#pragma unroll
      for (int mi = 0; mi < 4; ++mi)
#pragma unroll
        for (int nj = 0; nj < 4; ++nj)
          acc[mi][nj] = __builtin_amdgcn_mfma_f32_16x16x32_f16(af[mi], bv[nj], acc[mi][nj], 0, 0, 0);
      __builtin_amdgcn_s_setprio(0);
    }
    __builtin_amdgcn_sched_barrier(0);     // no next-STAGE sinking above barrier
    __builtin_amdgcn_s_barrier();          // reads done before buf re-staged
    buf ^= 1;
  }

  // epilogue: d = fmaf(-2^-11, acc, zn+en), top-2 within this 128-e tile
  float bestd[4][4], b2d[4][4]; int besti[4][4];
#pragma unroll
  for (int mi = 0; mi < 4; ++mi)
#pragma unroll
    for (int rg = 0; rg < 4; ++rg) { bestd[mi][rg] = 3.4e38f; b2d[mi][rg] = 3.4e38f; besti[mi][rg] = 0; }

#pragma unroll
  for (int nj = 0; nj < 4; ++nj) {
    int e = e0 + wc * 64 + nj * 16 + l15;
    float en = enorm[e];
#pragma unroll
    for (int mi = 0; mi < 4; ++mi)
#pragma unroll
      for (int rg = 0; rg < 4; ++rg) {
        float d = fmaf(NEG2_SCALE, acc[mi][nj][rg], __fadd_rn(znr[mi][rg], en));
        if (d < bestd[mi][rg]) {
          b2d[mi][rg] = bestd[mi][rg]; bestd[mi][rg] = d; besti[mi][rg] = e;
        } else if (d < b2d[mi][rg]) {
          b2d[mi][rg] = d;
        }
      }
  }

  float* redd = reinterpret_cast<float*>(&As[0][0]);
  int*   redi = reinterpret_cast<int*>(&As[0][0] + 1024);
  float* red2 = reinterpret_cast<float*>(&As[0][0] + 2048);

#pragma unroll
  for (int mi = 0; mi < 4; ++mi)
#pragma unroll
    for (int rg = 0; rg < 4; ++rg) {
      float bd = bestd[mi][rg]; int bi = besti[mi][rg]; float b2 = b2d[mi][rg];
#pragma unroll
      for (int m = 1; m < 16; m <<= 1) {
        float od = __shfl_xor(bd, m, 64);
        int   oi = __shfl_xor(bi, m, 64);
        float o2 = __shfl_xor(b2, m, 64);
        float hi = fmaxf(bd, od);
        b2 = fminf(fminf(b2, o2), hi);
        if (od < bd || (od == bd && oi < bi)) { bd = od; bi = oi; }
      }
      if (l15 == 0) {
        int lr = wr * 64 + mi * 16 + g * 4 + rg;
        redd[lr * 2 + wc] = bd; redi[lr * 2 + wc] = bi; red2[lr * 2 + wc] = b2;
      }
    }
  __syncthreads();

  if (tid < 128) {
    float d0 = redd[tid * 2], d1 = redd[tid * 2 + 1];
    int   i0 = redi[tid * 2], i1 = redi[tid * 2 + 1];
    float s0 = red2[tid * 2], s1 = red2[tid * 2 + 1];
    float bd; int bi;
    if (d1 < d0 || (d1 == d0 && i1 < i0)) { bd = d1; bi = i1; } else { bd = d0; bi = i0; }
    float b2 = fminf(fminf(s0, s1), fmaxf(d0, d1));
    size_t o = (size_t)(n0 + tid) * 8 + nb;
    pbd[o] = bd; pbi[o] = bi; pb2[o] = b2;
  }
#undef STAGE
}

// ---------------------------------------------------------------------------
// merge 8 per-block top-2 candidates per row; exact first-index tie-break
__global__ __launch_bounds__(256) void merge_kernel(
    const float* __restrict__ pbd, const int* __restrict__ pbi,
    const float* __restrict__ pb2,
    int* __restrict__ idx_out, float* __restrict__ loss_part,
    int* __restrict__ flag_cnt, int* __restrict__ flag_list) {
  int n = blockIdx.x * 256 + threadIdx.x;
  float bd = 3.4e38f; int bi = 0x7FFFFFFF; int bnb = -1;
#pragma unroll
  for (int nb = 0; nb < 8; ++nb) {
    float d = pbd[(size_t)n * 8 + nb];
    int   i = pbi[(size_t)n * 8 + nb];
    if (d < bd || (d == bd && i < bi)) { bd = d; bi = i; bnb = nb; }
  }
  float b2 = 3.4e38f;
#pragma unroll
  for (int nb = 0; nb < 8; ++nb) {
    float v = (nb == bnb) ? pb2[(size_t)n * 8 + nb] : pbd[(size_t)n * 8 + nb];
    b2 = fminf(b2, v);
  }
  idx_out[n] = bi;
  loss_part[n] = bd;
  if (b2 - bd < THETA) {
    int p = atomicAdd(flag_cnt, 1);
    flag_list[p] = n;
  }
}

// ---------------------------------------------------------------------------
// coalesced exact-fp32 repair: 4 flagged rows per block share one embT
// stream (4x less L2 traffic); per-row fmaf chain identical to the
// r1-certified arithmetic; first-index tie-break.
__global__ __launch_bounds__(256) void repair_kernel(
    const float* __restrict__ z, const float* __restrict__ embT,
    const float* __restrict__ znorm, const float* __restrict__ enorm,
    const int* __restrict__ flag_cnt, const int* __restrict__ flag_list,
    int* __restrict__ idx_out) {
  __shared__ float zrow[4][256];
  __shared__ float rd[256];
  __shared__ int   ri[256];
  const int t = threadIdx.x;
  const int cnt = flag_cnt[0] < NROWS ? flag_cnt[0] : NROWS;
  const int nquad = (cnt + 3) >> 2;
  const float4* embT4 = reinterpret_cast<const float4*>(embT);
  for (int j = blockIdx.x; j < nquad; j += gridDim.x) {
    int nr[4];
    __syncthreads();
#pragma unroll
    for (int r = 0; r < 4; ++r) {
      int jr = j * 4 + r;
      nr[r] = flag_list[jr < cnt ? jr : cnt - 1];
      zrow[r][t] = z[(size_t)(nr[r] >> 10) * ZB_STRIDE + (size_t)t * 1024 + (nr[r] & 1023)];
    }
    __syncthreads();
    float4 dot[4] = {{0.f,0.f,0.f,0.f},{0.f,0.f,0.f,0.f},{0.f,0.f,0.f,0.f},{0.f,0.f,0.f,0.f}};
    for (int k = 0; k < 256; ++k) {
      float4 v = embT4[k * 256 + t];
#pragma unroll
      for (int r = 0; r < 4; ++r) {
        float s = zrow[r][k];
        dot[r].x = fmaf(s, v.x, dot[r].x);
        dot[r].y = fmaf(s, v.y, dot[r].y);
        dot[r].z = fmaf(s, v.z, dot[r].z);
        dot[r].w = fmaf(s, v.w, dot[r].w);
      }
    }
#pragma unroll 1
    for (int r = 0; r < 4; ++r) {
      const float zn = znorm[nr[r]];
      float bd = 3.4e38f; int bi = 0;
      const float dv[4] = {dot[r].x, dot[r].y, dot[r].z, dot[r].w};
#pragma unroll
      for (int q = 0; q < 4; ++q) {
        int e = t * 4 + q;
        float d = __fsub_rn(__fadd_rn(zn, enorm[e]), __fmul_rn(2.0f, dv[q]));
        if (d < bd) { bd = d; bi = e; }
      }
      rd[t] = bd; ri[t] = bi;
      __syncthreads();
      for (int s2 = 128; s2 > 0; s2 >>= 1) {
        if (t < s2) {
          float od = rd[t + s2]; int oi = ri[t + s2];
          if (od < rd[t] || (od == rd[t] && oi < ri[t])) { rd[t] = od; ri[t] = oi; }
        }
        __syncthreads();
      }
      if (t == 0) idx_out[nr[r]] = ri[0];   // duplicate tail rows write same value
      __syncthreads();
    }
  }
}

// ---------------------------------------------------------------------------
__global__ __launch_bounds__(256) void onehot_kernel(const int* __restrict__ idx,
                                                     float* __restrict__ out_enc) {
  for (int i = blockIdx.x * 256 + threadIdx.x; i < NROWS * 256; i += 2048 * 256) {
    int n = i >> 8, j4 = i & 255;
    int e = idx[n];
    float4 v = {0.f, 0.f, 0.f, 0.f};
    if ((e >> 2) == j4) ((float*)&v)[e & 3] = 1.0f;
    reinterpret_cast<float4*>(out_enc)[i] = v;
  }
}

__global__ __launch_bounds__(256) void idxf_hist_kernel(const int* __restrict__ idx,
                                                        float* __restrict__ out_idxf,
                                                        int* __restrict__ hist) {
  int n = blockIdx.x * 256 + threadIdx.x;
  int e = idx[n];
  out_idxf[n] = (float)e;
  atomicAdd(&hist[e], 1);
}

__global__ __launch_bounds__(256) void gather_kernel(const float* __restrict__ emb,
                                                     const int* __restrict__ idx,
                                                     float* __restrict__ zq_out) {
  int bh = blockIdx.x;
  int b = bh >> 5, h = bh & 31;
  int t = threadIdx.x;
  int ww = t & 31;
  int gg = t >> 5;
  int n = b * 1024 + h * 32 + ww;
  int e = idx[n];
  const float* eb = emb + (size_t)e * CDIM;
  float* ob = zq_out + (size_t)b * ZB_STRIDE + h * 32 + ww;
#pragma unroll
  for (int u = 0; u < 32; ++u) {
    int c = gg * 32 + u;
    ob[(size_t)c * 1024] = eb[c];
  }
}

__global__ __launch_bounds__(256) void finalize_kernel(const float* __restrict__ loss_part,
                                                       const int* __restrict__ hist,
                                                       float* __restrict__ out_loss,
                                                       float* __restrict__ out_perp) {
  __shared__ float red[256];
  int t = threadIdx.x;
  float sum = 0.f;
  for (int i = t; i < NROWS; i += 256) sum += loss_part[i];
  red[t] = sum;
  __syncthreads();
  for (int s2 = 128; s2 > 0; s2 >>= 1) {
    if (t < s2) red[t] += red[t + s2];
    __syncthreads();
  }
  if (t == 0) out_loss[0] = 1.25f * (red[0] / 8388608.0f);
  __syncthreads();
  float hs = 0.f;
  for (int i = t; i < 1024; i += 256) {
    float em = (float)hist[i] / 32768.0f;
    hs += em * logf(em + 1e-10f);
  }
  red[t] = hs;
  __syncthreads();
  for (int s2 = 128; s2 > 0; s2 >>= 1) {
    if (t < s2) red[t] += red[t + s2];
    __syncthreads();
  }
  if (t == 0) out_perp[0] = expf(-red[0]);
}

// ---------------------------------------------------------------------------
extern "C" void kernel_launch(void* const* d_in, const int* in_sizes, int n_in,
                              void* d_out, int out_size, void* d_ws, size_t ws_size,
                              hipStream_t stream) {
  const float* z   = (const float*)d_in[0];
  const float* emb = (const float*)d_in[1];
  float* out = (float*)d_out;

  float* out_zq   = out + ZQ_OFF;
  float* out_loss = out + LOSS_OFF;
  float* out_perp = out + PERP_OFF;
  float* out_enc  = out + ENC_OFF;
  float* out_idxf = out + IDX_OFF;

  // workspace (small)
  int*   idx       = (int*)d_ws;                   // 32768
  int*   hist      = idx + NROWS;                  // 1024
  int*   flag_cnt  = hist + NE;                    // 4 (1 used)
  int*   flag_list = flag_cnt + 4;                 // 32768
  float* loss_part = (float*)(flag_list + NROWS);  // 32768
  float* znorm     = loss_part + NROWS;            // 32768
  float* enorm     = znorm + NROWS;                // 1024

  // staging buffers carved from the one-hot output region (overwritten later)
  unsigned short* zf16 = (unsigned short*)(out_enc + 2);   // 8388608 u16 (16B-aligned)
  unsigned short* ef16 = zf16 + (size_t)NROWS * CDIM;      // 262144 u16
  float*          embT = (float*)(ef16 + (size_t)NE * CDIM);// 262144 f32
  float*          pbd  = embT + 262144;                    // 262144 f32
  int*            pbi  = (int*)(pbd + 262144);             // 262144 i32
  float*          pb2  = (float*)(pbi + 262144);           // 262144 f32

  // hist (NE ints) and flag_cnt (adjacent) in one memset
  hipMemsetAsync(hist, 0, (NE + 1) * sizeof(int), stream);

  convert_z_kernel<<<512, 256, 0, stream>>>(z, zf16, znorm);
  convert_e_kernel<<<128, 256, 0, stream>>>(emb, ef16);
  enorm_kernel<<<NE / 256, 256, 0, stream>>>(emb, enorm);
  transpose_e_kernel<<<256, 256, 0, stream>>>(emb, embT);
  argmin_tile<<<2048, 256, 0, stream>>>(zf16, ef16, znorm, enorm, pbd, pbi, pb2);
  merge_kernel<<<NROWS / 256, 256, 0, stream>>>(pbd, pbi, pb2, idx, loss_part, flag_cnt, flag_list);
  repair_kernel<<<256, 256, 0, stream>>>(z, embT, znorm, enorm, flag_cnt, flag_list, idx);
  onehot_kernel<<<2048, 256, 0, stream>>>(idx, out_enc);
  idxf_hist_kernel<<<NROWS / 256, 256, 0, stream>>>(idx, out_idxf, hist);
  gather_kernel<<<1024, 256, 0, stream>>>(emb, idx, out_zq);
  finalize_kernel<<<1, 256, 0, stream>>>(loss_part, hist, out_loss, out_perp);
}

// Round 9
// 212.620 us; speedup vs baseline: 1.3974x; 1.0425x over previous
//
#include <hip/hip_runtime.h>
#include <math.h>

#define NROWS 32768
#define NE    1024
#define CDIM  256
#define ZB_STRIDE 262144

#define ZQ_OFF   0
#define LOSS_OFF 8388608
#define PERP_OFF 8388609
#define ENC_OFF  8388610
#define IDX_OFF  41943042

#define THETA 1.0e-4f
// e scaled by 2^12 before fp16 conversion; -2*dot = -2^-11 * acc
#define NEG2_SCALE (-0.00048828125f)

typedef _Float16 f16x8 __attribute__((ext_vector_type(8)));
typedef __attribute__((ext_vector_type(4))) float f32x4;
typedef __attribute__((ext_vector_type(8))) unsigned short ushort8;

// RNE float -> fp16 bits
__device__ __forceinline__ unsigned short f2h(float x) {
  _Float16 h = (_Float16)x;
  unsigned short u;
  __builtin_memcpy(&u, &h, 2);
  return u;
}

// ---------------------------------------------------------------------------
// numpy-pairwise-exact sum of squares (stride 1)
__device__ __forceinline__ float np_sumsq_256_s1(const float* __restrict__ base) {
  float tot[2];
#pragma unroll
  for (int hh = 0; hh < 2; ++hh) {
    float r[8];
#pragma unroll
    for (int j = 0; j < 8; ++j) {
      float x = base[hh * 128 + j];
      r[j] = __fmul_rn(x, x);
    }
    for (int i = 8; i < 128; i += 8) {
#pragma unroll
      for (int j = 0; j < 8; ++j) {
        float x = base[hh * 128 + i + j];
        r[j] = __fadd_rn(r[j], __fmul_rn(x, x));
      }
    }
    tot[hh] = __fadd_rn(__fadd_rn(__fadd_rn(r[0], r[1]), __fadd_rn(r[2], r[3])),
                        __fadd_rn(__fadd_rn(r[4], r[5]), __fadd_rn(r[6], r[7])));
  }
  return __fadd_rn(tot[0], tot[1]);
}

__global__ __launch_bounds__(256) void enorm_kernel(const float* __restrict__ emb,
                                                    float* __restrict__ enorm) {
  int n = blockIdx.x * 256 + threadIdx.x;
  enorm[n] = np_sumsq_256_s1(emb + (size_t)n * CDIM);
}

// emb fp32 -> fp16 (scaled 2^12), written in MFMA-fragment order:
// chunk16B = (((et*2+wc)*8 + kc)*4 + nj)*64 + g*16 + l15,
// holding e = et*128+wc*64+nj*16+l15, k = kc*32+g*8 .. +8
__global__ __launch_bounds__(256) void convert_e_kernel(const float* __restrict__ emb,
                                                        unsigned short* __restrict__ ef16r) {
  int cid = blockIdx.x * 256 + threadIdx.x;   // 0..32767
  int e = cid >> 5, cc = cid & 31;
  int kc = cc >> 2, g = cc & 3;
  int c0 = kc * 32 + g * 8;
  ushort8 o;
#pragma unroll
  for (int el = 0; el < 8; ++el) o[el] = f2h(emb[(size_t)e * 256 + c0 + el] * 4096.0f);
  int et = e >> 7, wcb = (e >> 6) & 1, nj = (e >> 4) & 3, l15e = e & 15;
  size_t chunk = ((((size_t)et * 2 + wcb) * 8 + kc) * 4 + nj) * 64 + (size_t)g * 16 + l15e;
  *reinterpret_cast<ushort8*>(ef16r + (chunk << 3)) = o;
}

// emb[e][c] -> embT[c][e] fp32 (for coalesced repair)
__global__ __launch_bounds__(256) void transpose_e_kernel(const float* __restrict__ emb,
                                                          float* __restrict__ embT) {
  __shared__ float tile[32][33];
  int be = blockIdx.x & 31, bc = blockIdx.x >> 5;
  int tx = threadIdx.x & 31, ty = threadIdx.x >> 5;
#pragma unroll
  for (int i = 0; i < 4; ++i)
    tile[ty + 8 * i][tx] = emb[(size_t)(be * 32 + ty + 8 * i) * 256 + bc * 32 + tx];
  __syncthreads();
#pragma unroll
  for (int i = 0; i < 4; ++i)
    embT[(size_t)(bc * 32 + ty + 8 * i) * 1024 + be * 32 + tx] = tile[tx][ty + 8 * i];
}

// ---------------------------------------------------------------------------
// z (b,c,h,w) fp32 -> zf16r (fragment order) + numpy-exact znorm.
// Norm accumulator tree identical to r4-verified version; only the write
// phase is redirected to fragment order:
// chunk16B = (((panel*2+wr)*8 + kc)*4 + mi)*64 + g*16 + l15,
// holding n = panel*128+wr*64+mi*16+l15, k = kc*32+g*8 .. +8
__global__ __launch_bounds__(256) void convert_z_kernel(const float* __restrict__ z,
                                                        unsigned short* __restrict__ zf16r,
                                                        float* __restrict__ znorm) {
  __shared__ unsigned short T16[64][266];
  __shared__ float accsF[2][8][16][4];
  const int t = threadIdx.x;
  const int b = blockIdx.x >> 4, hwt = blockIdx.x & 15;
  const int hw0 = hwt * 64;
  const int hw4 = t & 15;          // float4 unit within 64 hw
  const int jj = (t >> 4) & 7;     // np accumulator index
  const int hh = t >> 7;           // half
  const float* zb = z + (size_t)b * ZB_STRIDE + hw0 + hw4 * 4;

  float rr[4];
#pragma unroll
  for (int i = 0; i < 16; ++i) {
    int c = hh * 128 + jj + 8 * i;
    float4 v = *reinterpret_cast<const float4*>(zb + (size_t)c * 1024);
    const float xv[4] = {v.x, v.y, v.z, v.w};
#pragma unroll
    for (int q = 0; q < 4; ++q) {
      float p = __fmul_rn(xv[q], xv[q]);
      rr[q] = (i == 0) ? p : __fadd_rn(rr[q], p);
      T16[hw4 * 4 + q][c] = f2h(xv[q]);
    }
  }
#pragma unroll
  for (int q = 0; q < 4; ++q) accsF[hh][jj][hw4][q] = rr[q];
  __syncthreads();

  if (t < 64) {
    const int h4 = t >> 2, cq = t & 3;
    float tot[2];
#pragma unroll
    for (int half = 0; half < 2; ++half) {
      float r[8];
#pragma unroll
      for (int j = 0; j < 8; ++j) r[j] = accsF[half][j][h4][cq];
      tot[half] = __fadd_rn(__fadd_rn(__fadd_rn(r[0], r[1]), __fadd_rn(r[2], r[3])),
                            __fadd_rn(__fadd_rn(r[4], r[5]), __fadd_rn(r[6], r[7])));
    }
    znorm[b * 1024 + hw0 + t] = __fadd_rn(tot[0], tot[1]);
  }

  // write phase: fragment order. Block covers one (panel, wr) half:
  const int pw = b * 16 + hwt;        // = n0b >> 6
  const int panel = pw >> 1, wrh = pw & 1;
  const int l15w = t & 15, gw = (t >> 4) & 3, miw = t >> 6;
  const int rowW = miw * 16 + l15w;
#pragma unroll
  for (int kc = 0; kc < 8; ++kc) {
    ushort8 o;
#pragma unroll
    for (int el = 0; el < 8; ++el) o[el] = T16[rowW][kc * 32 + gw * 8 + el];
    size_t chunk = ((((size_t)panel * 2 + wrh) * 8 + kc) * 4 + miw) * 64 + (size_t)gw * 16 + l15w;
    *reinterpret_cast<ushort8*>(zf16r + (chunk << 3)) = o;
  }
}

// ---------------------------------------------------------------------------
// Register-fragment streaming fp16 MFMA argmin, v6:
//  * NO LDS staging, NO barriers in K-loop (r8 diagnosis: barrier+latency
//    dominated, MfmaUtil 6.8%). Operands pre-laid-out in fragment order;
//    each fragment = one coalesced 1KB global_load_dwordx4 per wave.
//  * Register contents per lane bit-identical to the r8 LDS path ->
//    identical MFMA results, epilogue/theta/repair semantics unchanged.
//  * 2-stage even/odd register pipeline (static names, rule 20); XCD
//    swizzle kept (A panel L2 reuse, FETCH ~16MB).
__global__ __launch_bounds__(256, 3) void argmin_tile(
    const unsigned short* __restrict__ zf16r, const unsigned short* __restrict__ ef16r,
    const float* __restrict__ znorm, const float* __restrict__ enorm,
    float* __restrict__ pbd, int* __restrict__ pbi, float* __restrict__ pb2) {
  __shared__ float redd[256];
  __shared__ int   redi[256];
  __shared__ float red2[256];

  const int tid = threadIdx.x;
  const int lane = tid & 63, w = tid >> 6;
  const int wr = w >> 1, wc = w & 1;
  const int l15 = lane & 15, g = lane >> 4;

  // XCD swizzle: xcd = bid&7 (HW round-robin); 32 row-panels x 8 e-tiles/XCD
  const int bid = blockIdx.x;
  const int nb = (bid >> 3) & 7;
  const int mb = (bid & 7) * 32 + (bid >> 6);
  const int n0 = mb * 128;
  const int e0 = nb * 128;

  float znr[4][4];
#pragma unroll
  for (int mi = 0; mi < 4; ++mi)
#pragma unroll
    for (int rg = 0; rg < 4; ++rg)
      znr[mi][rg] = znorm[n0 + wr * 64 + mi * 16 + g * 4 + rg];

  // fragment pointers (u16 units): chunk(kc,x) at base + (kc*4+x)*512
  const unsigned short* aP = zf16r + (size_t)(mb * 2 + wr) * 16384 + lane * 8;
  const unsigned short* bP = ef16r + (size_t)(nb * 2 + wc) * 16384 + lane * 8;

#define LDA(dst, kc)                                                           \
  { _Pragma("unroll")                                                          \
    for (int mi = 0; mi < 4; ++mi)                                             \
      dst[mi] = *reinterpret_cast<const f16x8*>(aP + ((kc) * 4 + mi) * 512); }
#define LDB(dst, kc)                                                           \
  { _Pragma("unroll")                                                          \
    for (int nj = 0; nj < 4; ++nj)                                             \
      dst[nj] = *reinterpret_cast<const f16x8*>(bP + ((kc) * 4 + nj) * 512); }
#define MFMA16(af, bv)                                                         \
  { __builtin_amdgcn_s_setprio(1);                                            \
    _Pragma("unroll")                                                          \
    for (int mi = 0; mi < 4; ++mi)                                             \
      _Pragma("unroll")                                                        \
      for (int nj = 0; nj < 4; ++nj)                                           \
        acc[mi][nj] = __builtin_amdgcn_mfma_f32_16x16x32_f16(af[mi], bv[nj],   \
                                                             acc[mi][nj], 0, 0, 0); \
    __builtin_amdgcn_s_setprio(0); }

  f32x4 acc[4][4];
  const f32x4 z4 = {0.f, 0.f, 0.f, 0.f};
#pragma unroll
  for (int mi = 0; mi < 4; ++mi)
#pragma unroll
    for (int nj = 0; nj < 4; ++nj) acc[mi][nj] = z4;

  f16x8 aE[4], bE[4], aO[4], bO[4];
  LDA(aE, 0); LDB(bE, 0);
#pragma unroll
  for (int kc = 0; kc < 8; ++kc) {
    if ((kc & 1) == 0) {
      if (kc < 7) { LDA(aO, kc + 1); LDB(bO, kc + 1); }
      MFMA16(aE, bE);
    } else {
      if (kc < 7) { LDA(aE, kc + 1); LDB(bE, kc + 1); }
      MFMA16(aO, bO);
    }
  }

  // epilogue: d = fmaf(-2^-11, acc, zn+en), top-2 within this 128-e tile
  float bestd[4][4], b2d[4][4]; int besti[4][4];
#pragma unroll
  for (int mi = 0; mi < 4; ++mi)
#pragma unroll
    for (int rg = 0; rg < 4; ++rg) { bestd[mi][rg] = 3.4e38f; b2d[mi][rg] = 3.4e38f; besti[mi][rg] = 0; }

#pragma unroll
  for (int nj = 0; nj < 4; ++nj) {
    int e = e0 + wc * 64 + nj * 16 + l15;
    float en = enorm[e];
#pragma unroll
    for (int mi = 0; mi < 4; ++mi)
#pragma unroll
      for (int rg = 0; rg < 4; ++rg) {
        float d = fmaf(NEG2_SCALE, acc[mi][nj][rg], __fadd_rn(znr[mi][rg], en));
        if (d < bestd[mi][rg]) {
          b2d[mi][rg] = bestd[mi][rg]; bestd[mi][rg] = d; besti[mi][rg] = e;
        } else if (d < b2d[mi][rg]) {
          b2d[mi][rg] = d;
        }
      }
  }

#pragma unroll
  for (int mi = 0; mi < 4; ++mi)
#pragma unroll
    for (int rg = 0; rg < 4; ++rg) {
      float bd = bestd[mi][rg]; int bi = besti[mi][rg]; float b2 = b2d[mi][rg];
#pragma unroll
      for (int m = 1; m < 16; m <<= 1) {
        float od = __shfl_xor(bd, m, 64);
        int   oi = __shfl_xor(bi, m, 64);
        float o2 = __shfl_xor(b2, m, 64);
        float hi = fmaxf(bd, od);
        b2 = fminf(fminf(b2, o2), hi);
        if (od < bd || (od == bd && oi < bi)) { bd = od; bi = oi; }
      }
      if (l15 == 0) {
        int lr = wr * 64 + mi * 16 + g * 4 + rg;
        redd[lr * 2 + wc] = bd; redi[lr * 2 + wc] = bi; red2[lr * 2 + wc] = b2;
      }
    }
  __syncthreads();

  if (tid < 128) {
    float d0 = redd[tid * 2], d1 = redd[tid * 2 + 1];
    int   i0 = redi[tid * 2], i1 = redi[tid * 2 + 1];
    float s0 = red2[tid * 2], s1 = red2[tid * 2 + 1];
    float bd; int bi;
    if (d1 < d0 || (d1 == d0 && i1 < i0)) { bd = d1; bi = i1; } else { bd = d0; bi = i0; }
    float b2 = fminf(fminf(s0, s1), fmaxf(d0, d1));
    size_t o = (size_t)(n0 + tid) * 8 + nb;
    pbd[o] = bd; pbi[o] = bi; pb2[o] = b2;
  }
#undef LDA
#undef LDB
#undef MFMA16
}

// ---------------------------------------------------------------------------
// merge 8 per-block top-2 candidates per row; exact first-index tie-break
__global__ __launch_bounds__(256) void merge_kernel(
    const float* __restrict__ pbd, const int* __restrict__ pbi,
    const float* __restrict__ pb2,
    int* __restrict__ idx_out, float* __restrict__ loss_part,
    int* __restrict__ flag_cnt, int* __restrict__ flag_list) {
  int n = blockIdx.x * 256 + threadIdx.x;
  float bd = 3.4e38f; int bi = 0x7FFFFFFF; int bnb = -1;
#pragma unroll
  for (int nb = 0; nb < 8; ++nb) {
    float d = pbd[(size_t)n * 8 + nb];
    int   i = pbi[(size_t)n * 8 + nb];
    if (d < bd || (d == bd && i < bi)) { bd = d; bi = i; bnb = nb; }
  }
  float b2 = 3.4e38f;
#pragma unroll
  for (int nb = 0; nb < 8; ++nb) {
    float v = (nb == bnb) ? pb2[(size_t)n * 8 + nb] : pbd[(size_t)n * 8 + nb];
    b2 = fminf(b2, v);
  }
  idx_out[n] = bi;
  loss_part[n] = bd;
  if (b2 - bd < THETA) {
    int p = atomicAdd(flag_cnt, 1);
    flag_list[p] = n;
  }
}

// ---------------------------------------------------------------------------
// coalesced exact-fp32 repair: 4 flagged rows per block share one embT
// stream; per-row fmaf chain identical to the r1-certified arithmetic.
__global__ __launch_bounds__(256) void repair_kernel(
    const float* __restrict__ z, const float* __restrict__ embT,
    const float* __restrict__ znorm, const float* __restrict__ enorm,
    const int* __restrict__ flag_cnt, const int* __restrict__ flag_list,
    int* __restrict__ idx_out) {
  __shared__ float zrow[4][256];
  __shared__ float rd[256];
  __shared__ int   ri[256];
  const int t = threadIdx.x;
  const int cnt = flag_cnt[0] < NROWS ? flag_cnt[0] : NROWS;
  const int nquad = (cnt + 3) >> 2;
  const float4* embT4 = reinterpret_cast<const float4*>(embT);
  for (int j = blockIdx.x; j < nquad; j += gridDim.x) {
    int nr[4];
    __syncthreads();
#pragma unroll
    for (int r = 0; r < 4; ++r) {
      int jr = j * 4 + r;
      nr[r] = flag_list[jr < cnt ? jr : cnt - 1];
      zrow[r][t] = z[(size_t)(nr[r] >> 10) * ZB_STRIDE + (size_t)t * 1024 + (nr[r] & 1023)];
    }
    __syncthreads();
    float4 dot[4] = {{0.f,0.f,0.f,0.f},{0.f,0.f,0.f,0.f},{0.f,0.f,0.f,0.f},{0.f,0.f,0.f,0.f}};
    for (int k = 0; k < 256; ++k) {
      float4 v = embT4[k * 256 + t];
#pragma unroll
      for (int r = 0; r < 4; ++r) {
        float s = zrow[r][k];
        dot[r].x = fmaf(s, v.x, dot[r].x);
        dot[r].y = fmaf(s, v.y, dot[r].y);
        dot[r].z = fmaf(s, v.z, dot[r].z);
        dot[r].w = fmaf(s, v.w, dot[r].w);
      }
    }
#pragma unroll 1
    for (int r = 0; r < 4; ++r) {
      const float zn = znorm[nr[r]];
      float bd = 3.4e38f; int bi = 0;
      const float dv[4] = {dot[r].x, dot[r].y, dot[r].z, dot[r].w};
#pragma unroll
      for (int q = 0; q < 4; ++q) {
        int e = t * 4 + q;
        float d = __fsub_rn(__fadd_rn(zn, enorm[e]), __fmul_rn(2.0f, dv[q]));
        if (d < bd) { bd = d; bi = e; }
      }
      rd[t] = bd; ri[t] = bi;
      __syncthreads();
      for (int s2 = 128; s2 > 0; s2 >>= 1) {
        if (t < s2) {
          float od = rd[t + s2]; int oi = ri[t + s2];
          if (od < rd[t] || (od == rd[t] && oi < ri[t])) { rd[t] = od; ri[t] = oi; }
        }
        __syncthreads();
      }
      if (t == 0) idx_out[nr[r]] = ri[0];   // duplicate tail rows write same value
      __syncthreads();
    }
  }
}

// ---------------------------------------------------------------------------
__global__ __launch_bounds__(256) void onehot_kernel(const int* __restrict__ idx,
                                                     float* __restrict__ out_enc) {
  for (int i = blockIdx.x * 256 + threadIdx.x; i < NROWS * 256; i += 2048 * 256) {
    int n = i >> 8, j4 = i & 255;
    int e = idx[n];
    float4 v = {0.f, 0.f, 0.f, 0.f};
    if ((e >> 2) == j4) ((float*)&v)[e & 3] = 1.0f;
    reinterpret_cast<float4*>(out_enc)[i] = v;
  }
}

__global__ __launch_bounds__(256) void idxf_hist_kernel(const int* __restrict__ idx,
                                                        float* __restrict__ out_idxf,
                                                        int* __restrict__ hist) {
  int n = blockIdx.x * 256 + threadIdx.x;
  int e = idx[n];
  out_idxf[n] = (float)e;
  atomicAdd(&hist[e], 1);
}

__global__ __launch_bounds__(256) void gather_kernel(const float* __restrict__ emb,
                                                     const int* __restrict__ idx,
                                                     float* __restrict__ zq_out) {
  int bh = blockIdx.x;
  int b = bh >> 5, h = bh & 31;
  int t = threadIdx.x;
  int ww = t & 31;
  int gg = t >> 5;
  int n = b * 1024 + h * 32 + ww;
  int e = idx[n];
  const float* eb = emb + (size_t)e * CDIM;
  float* ob = zq_out + (size_t)b * ZB_STRIDE + h * 32 + ww;
#pragma unroll
  for (int u = 0; u < 32; ++u) {
    int c = gg * 32 + u;
    ob[(size_t)c * 1024] = eb[c];
  }
}

__global__ __launch_bounds__(256) void finalize_kernel(const float* __restrict__ loss_part,
                                                       const int* __restrict__ hist,
                                                       float* __restrict__ out_loss,
                                                       float* __restrict__ out_perp) {
  __shared__ float red[256];
  int t = threadIdx.x;
  float sum = 0.f;
  for (int i = t; i < NROWS; i += 256) sum += loss_part[i];
  red[t] = sum;
  __syncthreads();
  for (int s2 = 128; s2 > 0; s2 >>= 1) {
    if (t < s2) red[t] += red[t + s2];
    __syncthreads();
  }
  if (t == 0) out_loss[0] = 1.25f * (red[0] / 8388608.0f);
  __syncthreads();
  float hs = 0.f;
  for (int i = t; i < 1024; i += 256) {
    float em = (float)hist[i] / 32768.0f;
    hs += em * logf(em + 1e-10f);
  }
  red[t] = hs;
  __syncthreads();
  for (int s2 = 128; s2 > 0; s2 >>= 1) {
    if (t < s2) red[t] += red[t + s2];
    __syncthreads();
  }
  if (t == 0) out_perp[0] = expf(-red[0]);
}

// ---------------------------------------------------------------------------
extern "C" void kernel_launch(void* const* d_in, const int* in_sizes, int n_in,
                              void* d_out, int out_size, void* d_ws, size_t ws_size,
                              hipStream_t stream) {
  const float* z   = (const float*)d_in[0];
  const float* emb = (const float*)d_in[1];
  float* out = (float*)d_out;

  float* out_zq   = out + ZQ_OFF;
  float* out_loss = out + LOSS_OFF;
  float* out_perp = out + PERP_OFF;
  float* out_enc  = out + ENC_OFF;
  float* out_idxf = out + IDX_OFF;

  // workspace (small)
  int*   idx       = (int*)d_ws;                   // 32768
  int*   hist      = idx + NROWS;                  // 1024
  int*   flag_cnt  = hist + NE;                    // 4 (1 used)
  int*   flag_list = flag_cnt + 4;                 // 32768
  float* loss_part = (float*)(flag_list + NROWS);  // 32768
  float* znorm     = loss_part + NROWS;            // 32768
  float* enorm     = znorm + NROWS;                // 1024

  // staging buffers carved from the one-hot output region (overwritten later)
  unsigned short* zf16r = (unsigned short*)(out_enc + 2);    // 8388608 u16 (16B-aligned)
  unsigned short* ef16r = zf16r + (size_t)NROWS * CDIM;      // 262144 u16
  float*          embT  = (float*)(ef16r + (size_t)NE * CDIM);// 262144 f32
  float*          pbd   = embT + 262144;                     // 262144 f32
  int*            pbi   = (int*)(pbd + 262144);              // 262144 i32
  float*          pb2   = (float*)(pbi + 262144);            // 262144 f32

  // hist (NE ints) and flag_cnt (adjacent) in one memset
  hipMemsetAsync(hist, 0, (NE + 1) * sizeof(int), stream);

  convert_z_kernel<<<512, 256, 0, stream>>>(z, zf16r, znorm);
  convert_e_kernel<<<128, 256, 0, stream>>>(emb, ef16r);
  enorm_kernel<<<NE / 256, 256, 0, stream>>>(emb, enorm);
  transpose_e_kernel<<<256, 256, 0, stream>>>(emb, embT);
  argmin_tile<<<2048, 256, 0, stream>>>(zf16r, ef16r, znorm, enorm, pbd, pbi, pb2);
  merge_kernel<<<NROWS / 256, 256, 0, stream>>>(pbd, pbi, pb2, idx, loss_part, flag_cnt, flag_list);
  repair_kernel<<<256, 256, 0, stream>>>(z, embT, znorm, enorm, flag_cnt, flag_list, idx);
  onehot_kernel<<<2048, 256, 0, stream>>>(idx, out_enc);
  idxf_hist_kernel<<<NROWS / 256, 256, 0, stream>>>(idx, out_idxf, hist);
  gather_kernel<<<1024, 256, 0, stream>>>(emb, idx, out_zq);
  finalize_kernel<<<1, 256, 0, stream>>>(loss_part, hist, out_loss, out_perp);
}

// Round 10
// 191.878 us; speedup vs baseline: 1.5485x; 1.1081x over previous
//
#include <hip/hip_runtime.h>
#include <math.h>

#define NROWS 32768
#define NE    1024
#define CDIM  256
#define ZB_STRIDE 262144

#define ZQ_OFF   0
#define LOSS_OFF 8388608
#define PERP_OFF 8388609
#define ENC_OFF  8388610
#define IDX_OFF  41943042

#define THETA 1.0e-4f
// e scaled by 2^12 before fp16 conversion; -2*dot = -2^-11 * acc
#define NEG2_SCALE (-0.00048828125f)

typedef _Float16 f16x8 __attribute__((ext_vector_type(8)));
typedef __attribute__((ext_vector_type(4))) float f32x4;
typedef __attribute__((ext_vector_type(8))) unsigned short ushort8;

// RNE float -> fp16 bits
__device__ __forceinline__ unsigned short f2h(float x) {
  _Float16 h = (_Float16)x;
  unsigned short u;
  __builtin_memcpy(&u, &h, 2);
  return u;
}

// ---------------------------------------------------------------------------
// numpy-pairwise-exact sum of squares (stride 1)
__device__ __forceinline__ float np_sumsq_256_s1(const float* __restrict__ base) {
  float tot[2];
#pragma unroll
  for (int hh = 0; hh < 2; ++hh) {
    float r[8];
#pragma unroll
    for (int j = 0; j < 8; ++j) {
      float x = base[hh * 128 + j];
      r[j] = __fmul_rn(x, x);
    }
    for (int i = 8; i < 128; i += 8) {
#pragma unroll
      for (int j = 0; j < 8; ++j) {
        float x = base[hh * 128 + i + j];
        r[j] = __fadd_rn(r[j], __fmul_rn(x, x));
      }
    }
    tot[hh] = __fadd_rn(__fadd_rn(__fadd_rn(r[0], r[1]), __fadd_rn(r[2], r[3])),
                        __fadd_rn(__fadd_rn(r[4], r[5]), __fadd_rn(r[6], r[7])));
  }
  return __fadd_rn(tot[0], tot[1]);
}

// ---------------------------------------------------------------------------
// Fused emb prep (role-split, bodies identical to r9's 3 kernels):
// blocks [0,128): fp32 -> fp16*2^12 in MFMA-fragment order
// blocks [128,384): emb -> embT fp32 transpose (for repair)
// blocks [384,388): numpy-exact enorm
__global__ __launch_bounds__(256) void prep_e(const float* __restrict__ emb,
                                              unsigned short* __restrict__ ef16r,
                                              float* __restrict__ embT,
                                              float* __restrict__ enorm) {
  const int bid = blockIdx.x;
  if (bid < 128) {
    int cid = bid * 256 + threadIdx.x;   // 0..32767
    int e = cid >> 5, cc = cid & 31;
    int kc = cc >> 2, g = cc & 3;
    int c0 = kc * 32 + g * 8;
    ushort8 o;
#pragma unroll
    for (int el = 0; el < 8; ++el) o[el] = f2h(emb[(size_t)e * 256 + c0 + el] * 4096.0f);
    int et = e >> 7, wcb = (e >> 6) & 1, nj = (e >> 4) & 3, l15e = e & 15;
    size_t chunk = ((((size_t)et * 2 + wcb) * 8 + kc) * 4 + nj) * 64 + (size_t)g * 16 + l15e;
    *reinterpret_cast<ushort8*>(ef16r + (chunk << 3)) = o;
  } else if (bid < 384) {
    __shared__ float tile[32][33];
    int tb = bid - 128;
    int be = tb & 31, bc = tb >> 5;
    int tx = threadIdx.x & 31, ty = threadIdx.x >> 5;
#pragma unroll
    for (int i = 0; i < 4; ++i)
      tile[ty + 8 * i][tx] = emb[(size_t)(be * 32 + ty + 8 * i) * 256 + bc * 32 + tx];
    __syncthreads();
#pragma unroll
    for (int i = 0; i < 4; ++i)
      embT[(size_t)(bc * 32 + ty + 8 * i) * 1024 + be * 32 + tx] = tile[tx][ty + 8 * i];
  } else {
    int n = (bid - 384) * 256 + threadIdx.x;
    enorm[n] = np_sumsq_256_s1(emb + (size_t)n * CDIM);
  }
}

// ---------------------------------------------------------------------------
// z (b,c,h,w) fp32 -> zf16r (fragment order) + numpy-exact znorm (r4-verified
// accumulator tree; unchanged from r9).
__global__ __launch_bounds__(256) void convert_z_kernel(const float* __restrict__ z,
                                                        unsigned short* __restrict__ zf16r,
                                                        float* __restrict__ znorm) {
  __shared__ unsigned short T16[64][266];
  __shared__ float accsF[2][8][16][4];
  const int t = threadIdx.x;
  const int b = blockIdx.x >> 4, hwt = blockIdx.x & 15;
  const int hw0 = hwt * 64;
  const int hw4 = t & 15;
  const int jj = (t >> 4) & 7;
  const int hh = t >> 7;
  const float* zb = z + (size_t)b * ZB_STRIDE + hw0 + hw4 * 4;

  float rr[4];
#pragma unroll
  for (int i = 0; i < 16; ++i) {
    int c = hh * 128 + jj + 8 * i;
    float4 v = *reinterpret_cast<const float4*>(zb + (size_t)c * 1024);
    const float xv[4] = {v.x, v.y, v.z, v.w};
#pragma unroll
    for (int q = 0; q < 4; ++q) {
      float p = __fmul_rn(xv[q], xv[q]);
      rr[q] = (i == 0) ? p : __fadd_rn(rr[q], p);
      T16[hw4 * 4 + q][c] = f2h(xv[q]);
    }
  }
#pragma unroll
  for (int q = 0; q < 4; ++q) accsF[hh][jj][hw4][q] = rr[q];
  __syncthreads();

  if (t < 64) {
    const int h4 = t >> 2, cq = t & 3;
    float tot[2];
#pragma unroll
    for (int half = 0; half < 2; ++half) {
      float r[8];
#pragma unroll
      for (int j = 0; j < 8; ++j) r[j] = accsF[half][j][h4][cq];
      tot[half] = __fadd_rn(__fadd_rn(__fadd_rn(r[0], r[1]), __fadd_rn(r[2], r[3])),
                            __fadd_rn(__fadd_rn(r[4], r[5]), __fadd_rn(r[6], r[7])));
    }
    znorm[b * 1024 + hw0 + t] = __fadd_rn(tot[0], tot[1]);
  }

  // write phase: fragment order
  const int pw = b * 16 + hwt;
  const int panel = pw >> 1, wrh = pw & 1;
  const int l15w = t & 15, gw = (t >> 4) & 3, miw = t >> 6;
  const int rowW = miw * 16 + l15w;
#pragma unroll
  for (int kc = 0; kc < 8; ++kc) {
    ushort8 o;
#pragma unroll
    for (int el = 0; el < 8; ++el) o[el] = T16[rowW][kc * 32 + gw * 8 + el];
    size_t chunk = ((((size_t)panel * 2 + wrh) * 8 + kc) * 4 + miw) * 64 + (size_t)gw * 16 + l15w;
    *reinterpret_cast<ushort8*>(zf16r + (chunk << 3)) = o;
  }
}

// ---------------------------------------------------------------------------
// Register-fragment streaming fp16 MFMA argmin, v7:
//  * wave tile 64 rows x 128 e (was 64x64): 4 A + 8 B frags -> 32 MFMA/kc
//    (intensity 2.67 vs 2.0 MFMA/KB); block = 128 rows x 256 e, grid 1024.
//    L2 traffic 512 -> 384 MB. acc 128 + 2-deep operands ~250 VGPR, 2 w/SIMD.
//  * no LDS staging, no K-loop barriers (r9); XCD-bijective swizzle kept.
//  * register contents/lane identical per fragment to r8/r9 -> epilogue,
//    theta, repair semantics unchanged.
__global__ __launch_bounds__(256, 2) void argmin_tile(
    const unsigned short* __restrict__ zf16r, const unsigned short* __restrict__ ef16r,
    const float* __restrict__ znorm, const float* __restrict__ enorm,
    float* __restrict__ pbd, int* __restrict__ pbi, float* __restrict__ pb2) {
  __shared__ float redd[256];
  __shared__ int   redi[256];
  __shared__ float red2[256];

  const int tid = threadIdx.x;
  const int lane = tid & 63, w = tid >> 6;
  const int wr = w >> 1, wc = w & 1;
  const int l15 = lane & 15, g = lane >> 4;

  // grid 1024: xcd = bid&7; per XCD 32 row-panels x 4 e-tiles (nb inner ->
  // 4 consecutive blocks share mb => A panel L2/L1 co-resident)
  const int bid = blockIdx.x;
  const int inner = bid >> 3;
  const int nb = inner & 3;
  const int mb = (bid & 7) * 32 + (inner >> 2);
  const int n0 = mb * 128;
  const int e0 = nb * 256;

  float znr[4][4];
#pragma unroll
  for (int mi = 0; mi < 4; ++mi)
#pragma unroll
    for (int rg = 0; rg < 4; ++rg)
      znr[mi][rg] = znorm[n0 + wr * 64 + mi * 16 + g * 4 + rg];

  // fragment pointers (u16 units)
  const unsigned short* aP = zf16r + (size_t)(mb * 2 + wr) * 16384 + lane * 8;
  const unsigned short* bP = ef16r + (size_t)(nb * 2 + wc) * 32768 + lane * 8;

#define LDA(dst, kc)                                                           \
  { _Pragma("unroll")                                                          \
    for (int mi = 0; mi < 4; ++mi)                                             \
      dst[mi] = *reinterpret_cast<const f16x8*>(aP + ((kc) * 4 + mi) * 512); }
#define LDB(dst, kc)                                                           \
  { _Pragma("unroll")                                                          \
    for (int njj = 0; njj < 8; ++njj)                                          \
      dst[njj] = *reinterpret_cast<const f16x8*>(                              \
          bP + (njj >> 2) * 16384 + (kc) * 2048 + (njj & 3) * 512); }
#define MFMA32(af, bv)                                                         \
  { __builtin_amdgcn_s_setprio(1);                                            \
    _Pragma("unroll")                                                          \
    for (int mi = 0; mi < 4; ++mi)                                             \
      _Pragma("unroll")                                                        \
      for (int njj = 0; njj < 8; ++njj)                                        \
        acc[mi][njj] = __builtin_amdgcn_mfma_f32_16x16x32_f16(af[mi], bv[njj], \
                                                              acc[mi][njj], 0, 0, 0); \
    __builtin_amdgcn_s_setprio(0); }

  f32x4 acc[4][8];
  const f32x4 z4 = {0.f, 0.f, 0.f, 0.f};
#pragma unroll
  for (int mi = 0; mi < 4; ++mi)
#pragma unroll
    for (int njj = 0; njj < 8; ++njj) acc[mi][njj] = z4;

  f16x8 aE[4], bE[8], aO[4], bO[8];
  LDA(aE, 0); LDB(bE, 0);
#pragma unroll
  for (int kc = 0; kc < 8; ++kc) {
    if ((kc & 1) == 0) {
      if (kc < 7) { LDA(aO, kc + 1); LDB(bO, kc + 1); }
      MFMA32(aE, bE);
    } else {
      if (kc < 7) { LDA(aE, kc + 1); LDB(bE, kc + 1); }
      MFMA32(aO, bO);
    }
  }

  // epilogue: d = fmaf(-2^-11, acc, zn+en), top-2 within this 256-e tile
  float bestd[4][4], b2d[4][4]; int besti[4][4];
#pragma unroll
  for (int mi = 0; mi < 4; ++mi)
#pragma unroll
    for (int rg = 0; rg < 4; ++rg) { bestd[mi][rg] = 3.4e38f; b2d[mi][rg] = 3.4e38f; besti[mi][rg] = 0; }

#pragma unroll
  for (int njj = 0; njj < 8; ++njj) {
    int e = e0 + wc * 128 + njj * 16 + l15;
    float en = enorm[e];
#pragma unroll
    for (int mi = 0; mi < 4; ++mi)
#pragma unroll
      for (int rg = 0; rg < 4; ++rg) {
        float d = fmaf(NEG2_SCALE, acc[mi][njj][rg], __fadd_rn(znr[mi][rg], en));
        if (d < bestd[mi][rg]) {
          b2d[mi][rg] = bestd[mi][rg]; bestd[mi][rg] = d; besti[mi][rg] = e;
        } else if (d < b2d[mi][rg]) {
          b2d[mi][rg] = d;
        }
      }
  }

#pragma unroll
  for (int mi = 0; mi < 4; ++mi)
#pragma unroll
    for (int rg = 0; rg < 4; ++rg) {
      float bd = bestd[mi][rg]; int bi = besti[mi][rg]; float b2 = b2d[mi][rg];
#pragma unroll
      for (int m = 1; m < 16; m <<= 1) {
        float od = __shfl_xor(bd, m, 64);
        int   oi = __shfl_xor(bi, m, 64);
        float o2 = __shfl_xor(b2, m, 64);
        float hi = fmaxf(bd, od);
        b2 = fminf(fminf(b2, o2), hi);
        if (od < bd || (od == bd && oi < bi)) { bd = od; bi = oi; }
      }
      if (l15 == 0) {
        int lr = wr * 64 + mi * 16 + g * 4 + rg;
        redd[lr * 2 + wc] = bd; redi[lr * 2 + wc] = bi; red2[lr * 2 + wc] = b2;
      }
    }
  __syncthreads();

  if (tid < 128) {
    float d0 = redd[tid * 2], d1 = redd[tid * 2 + 1];
    int   i0 = redi[tid * 2], i1 = redi[tid * 2 + 1];
    float s0 = red2[tid * 2], s1 = red2[tid * 2 + 1];
    float bd; int bi;
    if (d1 < d0 || (d1 == d0 && i1 < i0)) { bd = d1; bi = i1; } else { bd = d0; bi = i0; }
    float b2 = fminf(fminf(s0, s1), fmaxf(d0, d1));
    size_t o = (size_t)(n0 + tid) * 4 + nb;
    pbd[o] = bd; pbi[o] = bi; pb2[o] = b2;
  }
#undef LDA
#undef LDB
#undef MFMA32
}

// ---------------------------------------------------------------------------
// merge 4 per-block top-2 candidates per row; exact first-index tie-break
__global__ __launch_bounds__(256) void merge_kernel(
    const float* __restrict__ pbd, const int* __restrict__ pbi,
    const float* __restrict__ pb2,
    int* __restrict__ idx_out, float* __restrict__ loss_part,
    int* __restrict__ flag_cnt, int* __restrict__ flag_list) {
  int n = blockIdx.x * 256 + threadIdx.x;
  float bd = 3.4e38f; int bi = 0x7FFFFFFF; int bnb = -1;
#pragma unroll
  for (int nb = 0; nb < 4; ++nb) {
    float d = pbd[(size_t)n * 4 + nb];
    int   i = pbi[(size_t)n * 4 + nb];
    if (d < bd || (d == bd && i < bi)) { bd = d; bi = i; bnb = nb; }
  }
  float b2 = 3.4e38f;
#pragma unroll
  for (int nb = 0; nb < 4; ++nb) {
    float v = (nb == bnb) ? pb2[(size_t)n * 4 + nb] : pbd[(size_t)n * 4 + nb];
    b2 = fminf(b2, v);
  }
  idx_out[n] = bi;
  loss_part[n] = bd;
  if (b2 - bd < THETA) {
    int p = atomicAdd(flag_cnt, 1);
    flag_list[p] = n;
  }
}

// ---------------------------------------------------------------------------
// coalesced exact-fp32 repair: 4 flagged rows per block share one embT
// stream; per-row fmaf chain identical to the r1-certified arithmetic.
__global__ __launch_bounds__(256) void repair_kernel(
    const float* __restrict__ z, const float* __restrict__ embT,
    const float* __restrict__ znorm, const float* __restrict__ enorm,
    const int* __restrict__ flag_cnt, const int* __restrict__ flag_list,
    int* __restrict__ idx_out) {
  __shared__ float zrow[4][256];
  __shared__ float rd[256];
  __shared__ int   ri[256];
  const int t = threadIdx.x;
  const int cnt = flag_cnt[0] < NROWS ? flag_cnt[0] : NROWS;
  const int nquad = (cnt + 3) >> 2;
  const float4* embT4 = reinterpret_cast<const float4*>(embT);
  for (int j = blockIdx.x; j < nquad; j += gridDim.x) {
    int nr[4];
    __syncthreads();
#pragma unroll
    for (int r = 0; r < 4; ++r) {
      int jr = j * 4 + r;
      nr[r] = flag_list[jr < cnt ? jr : cnt - 1];
      zrow[r][t] = z[(size_t)(nr[r] >> 10) * ZB_STRIDE + (size_t)t * 1024 + (nr[r] & 1023)];
    }
    __syncthreads();
    float4 dot[4] = {{0.f,0.f,0.f,0.f},{0.f,0.f,0.f,0.f},{0.f,0.f,0.f,0.f},{0.f,0.f,0.f,0.f}};
    for (int k = 0; k < 256; ++k) {
      float4 v = embT4[k * 256 + t];
#pragma unroll
      for (int r = 0; r < 4; ++r) {
        float s = zrow[r][k];
        dot[r].x = fmaf(s, v.x, dot[r].x);
        dot[r].y = fmaf(s, v.y, dot[r].y);
        dot[r].z = fmaf(s, v.z, dot[r].z);
        dot[r].w = fmaf(s, v.w, dot[r].w);
      }
    }
#pragma unroll 1
    for (int r = 0; r < 4; ++r) {
      const float zn = znorm[nr[r]];
      float bd = 3.4e38f; int bi = 0;
      const float dv[4] = {dot[r].x, dot[r].y, dot[r].z, dot[r].w};
#pragma unroll
      for (int q = 0; q < 4; ++q) {
        int e = t * 4 + q;
        float d = __fsub_rn(__fadd_rn(zn, enorm[e]), __fmul_rn(2.0f, dv[q]));
        if (d < bd) { bd = d; bi = e; }
      }
      rd[t] = bd; ri[t] = bi;
      __syncthreads();
      for (int s2 = 128; s2 > 0; s2 >>= 1) {
        if (t < s2) {
          float od = rd[t + s2]; int oi = ri[t + s2];
          if (od < rd[t] || (od == rd[t] && oi < ri[t])) { rd[t] = od; ri[t] = oi; }
        }
        __syncthreads();
      }
      if (t == 0) idx_out[nr[r]] = ri[0];
      __syncthreads();
    }
  }
}

// ---------------------------------------------------------------------------
// Fused outputs (role-split, bodies identical to r9's 3 kernels):
// all 2048 blocks: one-hot streaming write; blocks [0,1024): z_q gather;
// blocks [1024,1152): idx-as-float + histogram.
__global__ __launch_bounds__(256) void outputs_kernel(const int* __restrict__ idx,
                                                      const float* __restrict__ emb,
                                                      float* __restrict__ out_enc,
                                                      float* __restrict__ out_idxf,
                                                      int* __restrict__ hist,
                                                      float* __restrict__ zq_out) {
  const int t = threadIdx.x;
  for (int i = blockIdx.x * 256 + t; i < NROWS * 256; i += 2048 * 256) {
    int n = i >> 8, j4 = i & 255;
    int e = idx[n];
    float4 v = {0.f, 0.f, 0.f, 0.f};
    if ((e >> 2) == j4) ((float*)&v)[e & 3] = 1.0f;
    reinterpret_cast<float4*>(out_enc)[i] = v;
  }
  if (blockIdx.x < 1024) {
    int bh = blockIdx.x;
    int b = bh >> 5, h = bh & 31;
    int ww = t & 31;
    int gg = t >> 5;
    int n = b * 1024 + h * 32 + ww;
    int e = idx[n];
    const float* eb = emb + (size_t)e * CDIM;
    float* ob = zq_out + (size_t)b * ZB_STRIDE + h * 32 + ww;
#pragma unroll
    for (int u = 0; u < 32; ++u) {
      int c = gg * 32 + u;
      ob[(size_t)c * 1024] = eb[c];
    }
  } else if (blockIdx.x < 1152) {
    int n = (blockIdx.x - 1024) * 256 + t;
    int e = idx[n];
    out_idxf[n] = (float)e;
    atomicAdd(&hist[e], 1);
  }
}

__global__ __launch_bounds__(256) void finalize_kernel(const float* __restrict__ loss_part,
                                                       const int* __restrict__ hist,
                                                       float* __restrict__ out_loss,
                                                       float* __restrict__ out_perp) {
  __shared__ float red[256];
  int t = threadIdx.x;
  float sum = 0.f;
  for (int i = t; i < NROWS; i += 256) sum += loss_part[i];
  red[t] = sum;
  __syncthreads();
  for (int s2 = 128; s2 > 0; s2 >>= 1) {
    if (t < s2) red[t] += red[t + s2];
    __syncthreads();
  }
  if (t == 0) out_loss[0] = 1.25f * (red[0] / 8388608.0f);
  __syncthreads();
  float hs = 0.f;
  for (int i = t; i < 1024; i += 256) {
    float em = (float)hist[i] / 32768.0f;
    hs += em * logf(em + 1e-10f);
  }
  red[t] = hs;
  __syncthreads();
  for (int s2 = 128; s2 > 0; s2 >>= 1) {
    if (t < s2) red[t] += red[t + s2];
    __syncthreads();
  }
  if (t == 0) out_perp[0] = expf(-red[0]);
}

// ---------------------------------------------------------------------------
extern "C" void kernel_launch(void* const* d_in, const int* in_sizes, int n_in,
                              void* d_out, int out_size, void* d_ws, size_t ws_size,
                              hipStream_t stream) {
  const float* z   = (const float*)d_in[0];
  const float* emb = (const float*)d_in[1];
  float* out = (float*)d_out;

  float* out_zq   = out + ZQ_OFF;
  float* out_loss = out + LOSS_OFF;
  float* out_perp = out + PERP_OFF;
  float* out_enc  = out + ENC_OFF;
  float* out_idxf = out + IDX_OFF;

  // workspace (small)
  int*   idx       = (int*)d_ws;                   // 32768
  int*   hist      = idx + NROWS;                  // 1024
  int*   flag_cnt  = hist + NE;                    // 4 (1 used)
  int*   flag_list = flag_cnt + 4;                 // 32768
  float* loss_part = (float*)(flag_list + NROWS);  // 32768
  float* znorm     = loss_part + NROWS;            // 32768
  float* enorm     = znorm + NROWS;                // 1024

  // staging buffers carved from the one-hot output region (overwritten later)
  unsigned short* zf16r = (unsigned short*)(out_enc + 2);    // 8388608 u16 (16B-aligned)
  unsigned short* ef16r = zf16r + (size_t)NROWS * CDIM;      // 262144 u16
  float*          embT  = (float*)(ef16r + (size_t)NE * CDIM);// 262144 f32
  float*          pbd   = embT + 262144;                     // 131072 f32 (slot 262144)
  int*            pbi   = (int*)(pbd + 262144);              // 131072 i32
  float*          pb2   = (float*)(pbi + 262144);            // 131072 f32

  // hist (NE ints) and flag_cnt (adjacent) in one memset
  hipMemsetAsync(hist, 0, (NE + 1) * sizeof(int), stream);

  convert_z_kernel<<<512, 256, 0, stream>>>(z, zf16r, znorm);
  prep_e<<<388, 256, 0, stream>>>(emb, ef16r, embT, enorm);
  argmin_tile<<<1024, 256, 0, stream>>>(zf16r, ef16r, znorm, enorm, pbd, pbi, pb2);
  merge_kernel<<<NROWS / 256, 256, 0, stream>>>(pbd, pbi, pb2, idx, loss_part, flag_cnt, flag_list);
  repair_kernel<<<256, 256, 0, stream>>>(z, embT, znorm, enorm, flag_cnt, flag_list, idx);
  outputs_kernel<<<2048, 256, 0, stream>>>(idx, emb, out_enc, out_idxf, hist, out_zq);
  finalize_kernel<<<1, 256, 0, stream>>>(loss_part, hist, out_loss, out_perp);
}